// Round 1
// baseline (381.199 us; speedup 1.0000x reference)
//
#include <hip/hip_runtime.h>
#include <hip/hip_bf16.h>
#include <stdint.h>

// Problem constants: B=4, SEG=1024, MEM=1024, TOTAL=2048, D=E=128, H=8
typedef __bf16 bf16;
typedef __attribute__((ext_vector_type(8))) __bf16 bf16x8;
typedef __attribute__((ext_vector_type(4))) float f32x4;

__device__ __forceinline__ f32x4 MFMA(bf16x8 a, bf16x8 b, f32x4 c) {
  // gfx950: D(16x16) = A(16x32)*B(32x16)+C, bf16 inputs, f32 accum.
  return __builtin_amdgcn_mfma_f32_16x16x32_bf16(a, b, c, 0, 0, 0);
}

__device__ __forceinline__ void GLL16(const void* g, void* l) {
  __builtin_amdgcn_global_load_lds(
      (const __attribute__((address_space(1))) void*)g,
      (__attribute__((address_space(3))) void*)l, 16, 0, 0);
}

__device__ __forceinline__ bf16 tobf(float f) { return (bf16)f; }

// ---------------- prep: pos encoding (fp64 trig) + weight transposes + bf16 converts ----------------
__global__ __launch_bounds__(256) void k_prep(
    const float* __restrict__ x, const float* __restrict__ mm,
    const float* __restrict__ wq, const float* __restrict__ wkv,
    const float* __restrict__ wr, const float* __restrict__ wmlp,
    bf16* __restrict__ posb, bf16* __restrict__ wq_bt, bf16* __restrict__ wkv_bt,
    bf16* __restrict__ wr_bt, bf16* __restrict__ wmlp_bt,
    bf16* __restrict__ xb, bf16* __restrict__ memb)
{
  int id = blockIdx.x * 256 + threadIdx.x;
  if (id < 262144) {  // posb[t][j], pos = enc[::-1] -> p = 2047 - t
    int t = id >> 7, j = id & 127;
    double p = (double)(2047 - t);
    double ang = p * pow(10000.0, -(double)j * (1.0 / 64.0));
    float v = (float)(((j & 1) == 0) ? sin(ang) : cos(ang));
    posb[id] = tobf(v);
    return;
  }
  id -= 262144;
  if (id < 131072) { int n = id >> 7, k = id & 127; wq_bt[id] = tobf(wq[k * 1024 + n]); return; }
  id -= 131072;
  if (id < 262144) { int n = id >> 7, k = id & 127; wkv_bt[id] = tobf(wkv[k * 2048 + n]); return; }
  id -= 262144;
  if (id < 131072) { int n = id >> 7, k = id & 127; wr_bt[id] = tobf(wr[k * 1024 + n]); return; }
  id -= 131072;
  if (id < 131072) { int n = id >> 10, k = id & 1023; wmlp_bt[id] = tobf(wmlp[k * 128 + n]); return; }
  id -= 131072;
  if (id < 524288) { xb[id] = tobf(x[id]); return; }
  id -= 524288;
  if (id < 524288) { memb[id] = tobf(mm[id]); return; }
}

// ---------------- projection GEMM: C[64x128 tile] = A[64x128] * W[128xN], scatter epilogue ----------------
// MODE 0: Q-proj (A=xb, out0=qh) / MODE 1: KV-proj (A=concat(memb,xb), out0=kh,out1=vh) / MODE 2: R-proj (A=posb, out0=rh)
template <int MODE>
__global__ __launch_bounds__(256, 2) void k_proj(
    const bf16* __restrict__ asrc, const bf16* __restrict__ asrc2,
    const bf16* __restrict__ wbt, bf16* __restrict__ out0, bf16* __restrict__ out1)
{
  __shared__ bf16 As[64 * 128];
  __shared__ bf16 Bs[128 * 128];
  const int m0 = blockIdx.x * 64;
  const int n0 = blockIdx.y * 128;
  const int tid = threadIdx.x;
  const int w = tid >> 6, lane = tid & 63, g = lane >> 4, c = lane & 15;

  // stage A: 1024 x 16B chunks, XOR chunk swizzle (chunk ^= row&7) applied on SOURCE
#pragma unroll
  for (int it = 0; it < 4; ++it) {
    int ch = w * 256 + it * 64 + lane;
    int row = ch >> 4, cc = ch & 15;
    int scc = cc ^ (row & 7);
    const bf16* src;
    if (MODE == 1) {
      int rg = m0 + row;
      int bb = rg >> 11, t = rg & 2047;
      src = (t < 1024) ? (asrc2 + (size_t)(bb * 1024 + t) * 128)
                       : (asrc + (size_t)(bb * 1024 + (t - 1024)) * 128);
    } else {
      src = asrc + (size_t)(m0 + row) * 128;
    }
    GLL16(src + scc * 8, (char*)As + (w * 256 + it * 64) * 16);
  }
  // stage B^T [128 n][128 k]
#pragma unroll
  for (int it = 0; it < 8; ++it) {
    int ch = w * 512 + it * 64 + lane;
    int n = ch >> 4, cc = ch & 15;
    int scc = cc ^ (n & 7);
    GLL16(wbt + (size_t)(n0 + n) * 128 + scc * 8, (char*)Bs + (w * 512 + it * 64) * 16);
  }
  __syncthreads();

  f32x4 acc[8] = {};
#pragma unroll
  for (int kk = 0; kk < 4; ++kk) {
    bf16x8 a = *(const bf16x8*)((const char*)As + (16 * w + c) * 256 + (((4 * kk + g) ^ (c & 7)) << 4));
#pragma unroll
    for (int fo = 0; fo < 8; ++fo) {
      bf16x8 b = *(const bf16x8*)((const char*)Bs + (16 * fo + c) * 256 + (((4 * kk + g) ^ (c & 7)) << 4));
      acc[fo] = MFMA(a, b, acc[fo]);
    }
  }

  // scatter epilogue (C/D: row = 4*g+j, col = c  [m89-verified])
#pragma unroll
  for (int fo = 0; fo < 8; ++fo) {
#pragma unroll
    for (int j = 0; j < 4; ++j) {
      int rg = m0 + 16 * w + 4 * g + j;
      int cg = n0 + 16 * fo + c;
      bf16 v = tobf(acc[fo][j]);
      if (MODE == 0) {
        int b = rg >> 10, s2 = rg & 1023;
        int nn = s2 >> 7;
        int s = ((s2 & 127) << 3) | (cg >> 7);
        int e = cg & 127;
        out0[((size_t)((b * 8 + nn) * 1024 + s)) * 128 + e] = v;
      } else if (MODE == 1) {
        int bb = rg >> 11, t = rg & 2047;
        int nn = (t >> 7) & 7;
        int hlf = (t >> 10) & 1;
        int t2 = ((t & 127) << 4) | (cg >> 7);
        int e = cg & 127;
        if (bb < 2)
          out0[((size_t)(((2 * bb + hlf) * 8 + nn) * 2048 + t2)) * 128 + e] = v;
        else
          out1[((size_t)(((2 * (bb - 2) + hlf) * 8 + nn) * 2048 + t2)) * 128 + e] = v;
      } else {
        int nn = rg >> 8;
        int t = ((rg & 255) << 3) | (cg >> 7);
        int e = cg & 127;
        out0[((size_t)(nn * 2048 + t)) * 128 + e] = v;
      }
    }
  }
}

// ---------------- V transpose: vh[bh][t][e] -> vht[bh][e][t] ----------------
__global__ __launch_bounds__(256) void k_vtrans(const bf16* __restrict__ vh, bf16* __restrict__ vht)
{
  __shared__ bf16 T[64][72];
  int bt = blockIdx.x * 64, be = blockIdx.y * 64, bh = blockIdx.z;
  const bf16* src = vh + (size_t)bh * 2048 * 128;
  bf16* dst = vht + (size_t)bh * 128 * 2048;
#pragma unroll
  for (int i2 = 0; i2 < 2; ++i2) {
    int ch = i2 * 256 + threadIdx.x;
    int tt = ch >> 3, cc = ch & 7;
    bf16x8 v = *(const bf16x8*)(src + (size_t)(bt + tt) * 128 + be + cc * 8);
    *(bf16x8*)&T[tt][cc * 8] = v;
  }
  __syncthreads();
#pragma unroll
  for (int i2 = 0; i2 < 2; ++i2) {
    int ch = i2 * 256 + threadIdx.x;
    int ee = ch >> 3, c2 = ch & 7;
    bf16x8 o;
#pragma unroll
    for (int m = 0; m < 8; ++m) o[m] = T[c2 * 8 + m][ee];
    *(bf16x8*)(dst + (size_t)(be + ee) * 2048 + bt + c2 * 8) = o;
  }
}

// ---------------- u1k[i,n,t] = u1[n]·k[i,n,t,:]  /  u2r[n,t] = u2[n]·r[n,t,:] ----------------
__global__ __launch_bounds__(256) void k_uterms(
    const bf16* __restrict__ kh, const bf16* __restrict__ rh,
    const float* __restrict__ u1, const float* __restrict__ u2,
    float* __restrict__ u1k, float* __restrict__ u2r)
{
  int id = blockIdx.x * 256 + threadIdx.x;
  if (id < 65536) {
    int n = (id >> 11) & 7;
    const bf16* kp = kh + (size_t)id * 128;  // id == (i*8+n)*2048 + t
    const float* up = u1 + n * 128;
    float s = 0.f;
#pragma unroll
    for (int c0 = 0; c0 < 128; c0 += 8) {
      bf16x8 kv = *(const bf16x8*)(kp + c0);
#pragma unroll
      for (int j = 0; j < 8; ++j) s += (float)kv[j] * up[c0 + j];
    }
    u1k[id] = s;
  } else {
    int id2 = id - 65536;
    int n = id2 >> 11;
    const bf16* rp = rh + (size_t)id2 * 128;  // id2 == n*2048 + t
    const float* up = u2 + n * 128;
    float s = 0.f;
#pragma unroll
    for (int c0 = 0; c0 < 128; c0 += 8) {
      bf16x8 rv = *(const bf16x8*)(rp + c0);
#pragma unroll
      for (int j = 0; j < 8; ++j) s += (float)rv[j] * up[c0 + j];
    }
    u2r[id2] = s;
  }
}

// ---------------- flash attention with TXL relative-shift bias ----------------
__global__ __launch_bounds__(256, 2) void k_flash(
    const bf16* __restrict__ qh, const bf16* __restrict__ kh,
    const bf16* __restrict__ vht, const bf16* __restrict__ rh,
    const float* __restrict__ u1k, const float* __restrict__ u2r,
    bf16* __restrict__ att2)
{
  __shared__ bf16 Ks[64 * 128];       // [t][e], XOR-swizzled 16B chunks
  __shared__ bf16 Vs[128 * 64];       // [e][t], XOR-swizzled
  __shared__ float QRP[4][16 * 91];   // per-wave QR scratch; aliased as bf16 P[16][72]

  const int qb = blockIdx.x, nh = blockIdx.y, ib = blockIdx.z;
  const int s0 = qb * 64;
  const int tid = threadIdx.x;
  const int w = tid >> 6, lane = tid & 63, g = lane >> 4, c = lane & 15;

  const bf16* qbase = qh + ((size_t)(ib * 8 + nh)) * 1024 * 128;
  const bf16* kbase = kh + ((size_t)(ib * 8 + nh)) * 2048 * 128;
  const bf16* vbase = vht + ((size_t)(ib * 8 + nh)) * 128 * 2048;
  const bf16* rbase = rh + (size_t)nh * 2048 * 128;
  const float* u1p = u1k + (ib * 8 + nh) * 2048;
  const float* u2p = u2r + nh * 2048;

  bf16x8 qf[4];
  {
    int srow = s0 + 16 * w + c;
#pragma unroll
    for (int kk = 0; kk < 4; ++kk)
      qf[kk] = *(const bf16x8*)(qbase + (size_t)srow * 128 + kk * 32 + g * 8);
  }

  f32x4 Ot[8] = {};
  float m_j[4], l_j[4];
#pragma unroll
  for (int j = 0; j < 4; ++j) { m_j[j] = -1e30f; l_j[j] = 0.f; }

  const float KSC = 1.4426950408889634f / 11.313708498984761f;  // log2(e)/sqrt(128)
  const int nt = qb + 17;  // keys needed: t <= s0+63+1024

  for (int tt = 0; tt < nt; ++tt) {
    const int t0 = tt * 64;
    __syncthreads();
#pragma unroll
    for (int it = 0; it < 4; ++it) {  // stage K tile
      int ch = w * 256 + it * 64 + lane;
      int row = ch >> 4, cc = ch & 15;
      GLL16(kbase + (size_t)(t0 + row) * 128 + ((cc ^ (row & 7)) * 8),
            (char*)Ks + (w * 256 + it * 64) * 16);
    }
#pragma unroll
    for (int it = 0; it < 4; ++it) {  // stage V^T tile
      int ch = w * 256 + it * 64 + lane;
      int e = ch >> 3, tc = ch & 7;
      GLL16(vbase + (size_t)e * 2048 + t0 + ((tc ^ (e & 7)) * 8),
            (char*)Vs + (w * 256 + it * 64) * 16);
    }
    __syncthreads();

    // ---- S = Q K^T ----
    f32x4 sacc[4] = {};
#pragma unroll
    for (int kk = 0; kk < 4; ++kk) {
#pragma unroll
      for (int f = 0; f < 4; ++f) {
        bf16x8 kf = *(const bf16x8*)((const char*)Ks + (16 * f + c) * 256 + (((4 * kk + g) ^ (c & 7)) << 4));
        sacc[f] = MFMA(qf[kk], kf, sacc[f]);
      }
    }
    // ---- bias: QR over the 80-wide u-window (u = t - s - 1025 mod 2048) ----
    f32x4 bacc[5] = {};
    const int wb = t0 - s0 - 16 * w - 1040 + 4096;
#pragma unroll
    for (int f2 = 0; f2 < 5; ++f2) {
      int u = (wb + 16 * f2 + c) & 2047;
      const bf16* rrow = rbase + (size_t)u * 128;
#pragma unroll
      for (int kk = 0; kk < 4; ++kk) {
        bf16x8 rf = *(const bf16x8*)(rrow + kk * 32 + g * 8);
        bacc[f2] = MFMA(qf[kk], rf, bacc[f2]);
      }
    }
    float* qr = &QRP[w][0];
#pragma unroll
    for (int f2 = 0; f2 < 5; ++f2)
#pragma unroll
      for (int j = 0; j < 4; ++j)
        qr[(4 * g + j) * 91 + 16 * f2 + c] = bacc[f2][j];

    // ---- compose scores (bias gather: local col = 16f + c - il + 15) ----
    float u1v[4], u2v[4];
#pragma unroll
    for (int f = 0; f < 4; ++f) { int tg = t0 + 16 * f + c; u1v[f] = u1p[tg]; u2v[f] = u2p[tg]; }
    const bool lastT = (tt == nt - 1);
    float zv[4][4];
#pragma unroll
    for (int f = 0; f < 4; ++f) {
#pragma unroll
      for (int j = 0; j < 4; ++j) {
        int il = 4 * g + j;
        float bias = qr[il * 91 + (16 * f + c - il + 15)];
        float z = (sacc[f][j] + bias + u1v[f] + u2v[f]) * KSC;
        if (lastT && (16 * f + c > 16 * w + il)) z = -1e30f;
        zv[f][j] = z;
      }
    }
    // ---- online softmax (base 2), rows live in 16-lane groups ----
    float alpha[4];
#pragma unroll
    for (int j = 0; j < 4; ++j) {
      float tm = fmaxf(fmaxf(zv[0][j], zv[1][j]), fmaxf(zv[2][j], zv[3][j]));
#pragma unroll
      for (int d = 1; d < 16; d <<= 1) tm = fmaxf(tm, __shfl_xor(tm, d));
      float mn = fmaxf(m_j[j], tm);
      alpha[j] = exp2f(m_j[j] - mn);
      m_j[j] = mn;
      float ps = 0.f;
#pragma unroll
      for (int f = 0; f < 4; ++f) { float pp = exp2f(zv[f][j] - mn); zv[f][j] = pp; ps += pp; }
#pragma unroll
      for (int d = 1; d < 16; d <<= 1) ps += __shfl_xor(ps, d);
      l_j[j] = l_j[j] * alpha[j] + ps;
    }
#pragma unroll
    for (int fo = 0; fo < 8; ++fo)
#pragma unroll
      for (int j = 0; j < 4; ++j) Ot[fo][j] *= alpha[j];

    // ---- P -> per-wave LDS (bf16, row-major [16][72]) ----
    bf16* pb = (bf16*)&QRP[w][0];
#pragma unroll
    for (int f = 0; f < 4; ++f)
#pragma unroll
      for (int j = 0; j < 4; ++j)
        pb[(4 * g + j) * 72 + 16 * f + c] = tobf(zv[f][j]);

    // ---- O += P V ----
#pragma unroll
    for (int kk2 = 0; kk2 < 2; ++kk2) {
      bf16x8 pa = *(const bf16x8*)(pb + c * 72 + kk2 * 32 + g * 8);
#pragma unroll
      for (int fo = 0; fo < 8; ++fo) {
        int e = 16 * fo + c;
        bf16x8 vf = *(const bf16x8*)((const char*)Vs + e * 128 + (((4 * kk2 + g) ^ (c & 7)) << 4));
        Ot[fo] = MFMA(pa, vf, Ot[fo]);
      }
    }
  }

  // ---- epilogue: divide by l, scatter into att2[b, n*128+s/8, (s%8)*128+e] ----
  bf16* ob = att2 + (size_t)ib * 1024 * 1024;
#pragma unroll
  for (int j = 0; j < 4; ++j) {
    int sg = s0 + 16 * w + 4 * g + j;
    size_t rowb = (size_t)(nh * 128 + (sg >> 3)) * 1024 + ((sg & 7) << 7);
    float inv = 1.f / l_j[j];
#pragma unroll
    for (int fo = 0; fo < 8; ++fo)
      ob[rowb + 16 * fo + c] = tobf(Ot[fo][j] * inv);
  }
}

// ---------------- y = att2 @ w_mlp + x, then LayerNorm ----------------
__global__ __launch_bounds__(256, 2) void k_mlp(
    const bf16* __restrict__ att2, const bf16* __restrict__ wmlp_bt,
    const float* __restrict__ x, const float* __restrict__ lng, const float* __restrict__ lnb,
    float* __restrict__ out)
{
  __shared__ bf16 As[64 * 128];
  __shared__ bf16 Bs[128 * 128];
  const int m0 = blockIdx.x * 64;
  const int tid = threadIdx.x;
  const int w = tid >> 6, lane = tid & 63, g = lane >> 4, c = lane & 15;

  f32x4 acc[8] = {};
  for (int ks = 0; ks < 8; ++ks) {
    int k0 = ks * 128;
    __syncthreads();
#pragma unroll
    for (int it = 0; it < 4; ++it) {
      int ch = w * 256 + it * 64 + lane;
      int row = ch >> 4, cc = ch & 15;
      GLL16(att2 + (size_t)(m0 + row) * 1024 + k0 + ((cc ^ (row & 7)) * 8),
            (char*)As + (w * 256 + it * 64) * 16);
    }
#pragma unroll
    for (int it = 0; it < 8; ++it) {
      int ch = w * 512 + it * 64 + lane;
      int n = ch >> 4, cc = ch & 15;
      GLL16(wmlp_bt + (size_t)n * 1024 + k0 + ((cc ^ (n & 7)) * 8),
            (char*)Bs + (w * 512 + it * 64) * 16);
    }
    __syncthreads();
#pragma unroll
    for (int kk = 0; kk < 4; ++kk) {
      bf16x8 a = *(const bf16x8*)((const char*)As + (16 * w + c) * 256 + (((4 * kk + g) ^ (c & 7)) << 4));
#pragma unroll
      for (int fo = 0; fo < 8; ++fo) {
        bf16x8 b = *(const bf16x8*)((const char*)Bs + (16 * fo + c) * 256 + (((4 * kk + g) ^ (c & 7)) << 4));
        acc[fo] = MFMA(a, b, acc[fo]);
      }
    }
  }
  // epilogue: + x residual, LayerNorm over 128
#pragma unroll
  for (int j = 0; j < 4; ++j) {
    int rg = m0 + 16 * w + 4 * g + j;
    float y[8];
    float s1 = 0.f, s2 = 0.f;
#pragma unroll
    for (int fo = 0; fo < 8; ++fo) {
      float v = acc[fo][j] + x[(size_t)rg * 128 + 16 * fo + c];
      y[fo] = v; s1 += v; s2 += v * v;
    }
#pragma unroll
    for (int d = 1; d < 16; d <<= 1) { s1 += __shfl_xor(s1, d); s2 += __shfl_xor(s2, d); }
    float mu = s1 * 0.0078125f;
    float var = s2 * 0.0078125f - mu * mu;
    float rs = rsqrtf(var + 1e-5f);
#pragma unroll
    for (int fo = 0; fo < 8; ++fo) {
      int e = 16 * fo + c;
      out[(size_t)rg * 128 + e] = (y[fo] - mu) * rs * lng[e] + lnb[e];
    }
  }
}

extern "C" void kernel_launch(void* const* d_in, const int* in_sizes, int n_in,
                              void* d_out, int out_size, void* d_ws, size_t ws_size,
                              hipStream_t stream)
{
  const float* x    = (const float*)d_in[0];
  const float* mm   = (const float*)d_in[1];
  // d_in[2] = att_mask (all false, unused by the reference math)
  const float* u1   = (const float*)d_in[3];
  const float* u2   = (const float*)d_in[4];
  const float* wq   = (const float*)d_in[5];
  const float* wkv  = (const float*)d_in[6];
  const float* wr   = (const float*)d_in[7];
  const float* wmlp = (const float*)d_in[8];
  const float* lng  = (const float*)d_in[9];
  const float* lnb  = (const float*)d_in[10];
  float* out = (float*)d_out;

  char* p = (char*)d_ws;
  bf16* posb    = (bf16*)p;  p += (size_t)262144 * 2;
  bf16* wq_bt   = (bf16*)p;  p += (size_t)131072 * 2;
  bf16* wkv_bt  = (bf16*)p;  p += (size_t)262144 * 2;
  bf16* wr_bt   = (bf16*)p;  p += (size_t)131072 * 2;
  bf16* wmlp_bt = (bf16*)p;  p += (size_t)131072 * 2;
  bf16* xb      = (bf16*)p;  p += (size_t)524288 * 2;
  bf16* memb    = (bf16*)p;  p += (size_t)524288 * 2;
  bf16* qh      = (bf16*)p;  p += (size_t)4 * 8 * 1024 * 128 * 2;
  bf16* kh      = (bf16*)p;  p += (size_t)4 * 8 * 2048 * 128 * 2;
  bf16* vh      = (bf16*)p;  p += (size_t)4 * 8 * 2048 * 128 * 2;
  bf16* vht     = (bf16*)p;  p += (size_t)4 * 8 * 2048 * 128 * 2;
  bf16* rh      = (bf16*)p;  p += (size_t)8 * 2048 * 128 * 2;
  float* u1kv   = (float*)p; p += (size_t)65536 * 4;
  float* u2rv   = (float*)p; p += (size_t)16384 * 4;
  bf16* att2    = (bf16*)p;  p += (size_t)4 * 1024 * 1024 * 2;

  k_prep<<<dim3(7680), dim3(256), 0, stream>>>(x, mm, wq, wkv, wr, wmlp,
                                               posb, wq_bt, wkv_bt, wr_bt, wmlp_bt, xb, memb);
  k_proj<0><<<dim3(64, 8),  dim3(256), 0, stream>>>(xb,  (const bf16*)nullptr, wq_bt,  qh, (bf16*)nullptr);
  k_proj<1><<<dim3(128, 16), dim3(256), 0, stream>>>(xb,  memb,                wkv_bt, kh, vh);
  k_proj<2><<<dim3(32, 8),  dim3(256), 0, stream>>>(posb, (const bf16*)nullptr, wr_bt,  rh, (bf16*)nullptr);
  k_vtrans<<<dim3(32, 2, 32), dim3(256), 0, stream>>>(vh, vht);
  k_uterms<<<dim3(320), dim3(256), 0, stream>>>(kh, rh, u1, u2, u1kv, u2rv);
  k_flash<<<dim3(16, 8, 4), dim3(256), 0, stream>>>(qh, kh, vht, rh, u1kv, u2rv, att2);
  k_mlp<<<dim3(64), dim3(256), 0, stream>>>(att2, wmlp_bt, x, lng, lnb, out);
}

// Round 2
// 318.366 us; speedup vs baseline: 1.1974x; 1.1974x over previous
//
#include <hip/hip_runtime.h>
#include <hip/hip_bf16.h>
#include <stdint.h>

// Problem constants: B=4, SEG=1024, MEM=1024, TOTAL=2048, D=E=128, H=8
typedef __bf16 bf16;
typedef __attribute__((ext_vector_type(8))) __bf16 bf16x8;
typedef __attribute__((ext_vector_type(4))) float f32x4;

#define KSC 0.12764932952880681f  // log2(e)/sqrt(128)

__device__ __forceinline__ f32x4 MFMA(bf16x8 a, bf16x8 b, f32x4 c) {
  return __builtin_amdgcn_mfma_f32_16x16x32_bf16(a, b, c, 0, 0, 0);
}

__device__ __forceinline__ void GLL16(const void* g, void* l) {
  __builtin_amdgcn_global_load_lds(
      (const __attribute__((address_space(1))) void*)g,
      (__attribute__((address_space(3))) void*)l, 16, 0, 0);
}

__device__ __forceinline__ bf16 tobf(float f) { return (bf16)f; }

// ---------------- prep: pos encoding (fp32 trig) + weight transposes + bf16 converts ----------------
__global__ __launch_bounds__(256) void k_prep(
    const float* __restrict__ x, const float* __restrict__ mm,
    const float* __restrict__ wq, const float* __restrict__ wkv,
    const float* __restrict__ wr, const float* __restrict__ wmlp,
    bf16* __restrict__ posb, bf16* __restrict__ wq_bt, bf16* __restrict__ wkv_bt,
    bf16* __restrict__ wr_bt, bf16* __restrict__ wmlp_bt,
    bf16* __restrict__ xb, bf16* __restrict__ memb)
{
  int id = blockIdx.x * 256 + threadIdx.x;
  if (id < 262144) {  // posb[t][j], pos = enc[::-1] -> p = 2047 - t
    int t = id >> 7, j = id & 127;
    float p = (float)(2047 - t);
    float ang = p * exp2f(-(float)j * 0.20762050593046264f);  // 10000^(-j/64)
    float v = ((j & 1) == 0) ? sinf(ang) : cosf(ang);
    posb[id] = tobf(v);
    return;
  }
  id -= 262144;
  if (id < 131072) { int n = id >> 7, k = id & 127; wq_bt[id] = tobf(wq[k * 1024 + n]); return; }
  id -= 131072;
  if (id < 262144) { int n = id >> 7, k = id & 127; wkv_bt[id] = tobf(wkv[k * 2048 + n]); return; }
  id -= 262144;
  if (id < 131072) { int n = id >> 7, k = id & 127; wr_bt[id] = tobf(wr[k * 1024 + n]); return; }
  id -= 131072;
  if (id < 131072) { int n = id >> 10, k = id & 1023; wmlp_bt[id] = tobf(wmlp[k * 128 + n]); return; }
  id -= 131072;
  if (id < 524288) { xb[id] = tobf(x[id]); return; }
  id -= 524288;
  if (id < 524288) { memb[id] = tobf(mm[id]); return; }
}

// ---------------- projection GEMM: C[64x128 tile] = A[64x128] * W[128xN], scatter epilogue ----------------
template <int MODE>
__global__ __launch_bounds__(256, 2) void k_proj(
    const bf16* __restrict__ asrc, const bf16* __restrict__ asrc2,
    const bf16* __restrict__ wbt, bf16* __restrict__ out0, bf16* __restrict__ out1,
    float oscale)
{
  __shared__ bf16 As[64 * 128];
  __shared__ bf16 Bs[128 * 128];
  const int m0 = blockIdx.x * 64;
  const int n0 = blockIdx.y * 128;
  const int tid = threadIdx.x;
  const int w = tid >> 6, lane = tid & 63, g = lane >> 4, c = lane & 15;

#pragma unroll
  for (int it = 0; it < 4; ++it) {
    int ch = w * 256 + it * 64 + lane;
    int row = ch >> 4, cc = ch & 15;
    int scc = cc ^ (row & 7);
    const bf16* src;
    if (MODE == 1) {
      int rg = m0 + row;
      int bb = rg >> 11, t = rg & 2047;
      src = (t < 1024) ? (asrc2 + (size_t)(bb * 1024 + t) * 128)
                       : (asrc + (size_t)(bb * 1024 + (t - 1024)) * 128);
    } else {
      src = asrc + (size_t)(m0 + row) * 128;
    }
    GLL16(src + scc * 8, (char*)As + (w * 256 + it * 64) * 16);
  }
#pragma unroll
  for (int it = 0; it < 8; ++it) {
    int ch = w * 512 + it * 64 + lane;
    int n = ch >> 4, cc = ch & 15;
    int scc = cc ^ (n & 7);
    GLL16(wbt + (size_t)(n0 + n) * 128 + scc * 8, (char*)Bs + (w * 512 + it * 64) * 16);
  }
  __syncthreads();

  f32x4 acc[8] = {};
#pragma unroll
  for (int kk = 0; kk < 4; ++kk) {
    bf16x8 a = *(const bf16x8*)((const char*)As + (16 * w + c) * 256 + (((4 * kk + g) ^ (c & 7)) << 4));
#pragma unroll
    for (int fo = 0; fo < 8; ++fo) {
      bf16x8 b = *(const bf16x8*)((const char*)Bs + (16 * fo + c) * 256 + (((4 * kk + g) ^ (c & 7)) << 4));
      acc[fo] = MFMA(a, b, acc[fo]);
    }
  }

#pragma unroll
  for (int fo = 0; fo < 8; ++fo) {
#pragma unroll
    for (int j = 0; j < 4; ++j) {
      int rg = m0 + 16 * w + 4 * g + j;
      int cg = n0 + 16 * fo + c;
      bf16 v = tobf(acc[fo][j] * oscale);
      if (MODE == 0) {
        int b = rg >> 10, s2 = rg & 1023;
        int nn = s2 >> 7;
        int s = ((s2 & 127) << 3) | (cg >> 7);
        int e = cg & 127;
        out0[((size_t)((b * 8 + nn) * 1024 + s)) * 128 + e] = v;
      } else if (MODE == 1) {
        int bb = rg >> 11, t = rg & 2047;
        int nn = (t >> 7) & 7;
        int hlf = (t >> 10) & 1;
        int t2 = ((t & 127) << 4) | (cg >> 7);
        int e = cg & 127;
        if (bb < 2)
          out0[((size_t)(((2 * bb + hlf) * 8 + nn) * 2048 + t2)) * 128 + e] = v;
        else
          out1[((size_t)(((2 * (bb - 2) + hlf) * 8 + nn) * 2048 + t2)) * 128 + e] = v;
      } else {
        int nn = rg >> 8;
        int t = ((rg & 255) << 3) | (cg >> 7);
        int e = cg & 127;
        out0[((size_t)(nn * 2048 + t)) * 128 + e] = v;
      }
    }
  }
}

// ---------------- V transpose: vh[bh][t][e] -> vht[bh][e][t] ----------------
__global__ __launch_bounds__(256) void k_vtrans(const bf16* __restrict__ vh, bf16* __restrict__ vht)
{
  __shared__ bf16 T[64][72];
  int bt = blockIdx.x * 64, be = blockIdx.y * 64, bh = blockIdx.z;
  const bf16* src = vh + (size_t)bh * 2048 * 128;
  bf16* dst = vht + (size_t)bh * 128 * 2048;
#pragma unroll
  for (int i2 = 0; i2 < 2; ++i2) {
    int ch = i2 * 256 + threadIdx.x;
    int tt = ch >> 3, cc = ch & 7;
    bf16x8 v = *(const bf16x8*)(src + (size_t)(bt + tt) * 128 + be + cc * 8);
    *(bf16x8*)&T[tt][cc * 8] = v;
  }
  __syncthreads();
#pragma unroll
  for (int i2 = 0; i2 < 2; ++i2) {
    int ch = i2 * 256 + threadIdx.x;
    int ee = ch >> 3, c2 = ch & 7;
    bf16x8 o;
#pragma unroll
    for (int m = 0; m < 8; ++m) o[m] = T[c2 * 8 + m][ee];
    *(bf16x8*)(dst + (size_t)(be + ee) * 2048 + bt + c2 * 8) = o;
  }
}

// ---------------- uu[bh][t] = (u1[n]·k[bh,t,:] + u2[n]·r[n,t,:]) * KSC ----------------
__global__ __launch_bounds__(256) void k_uterms(
    const bf16* __restrict__ kh, const bf16* __restrict__ rh,
    const float* __restrict__ u1, const float* __restrict__ u2,
    float* __restrict__ uu)
{
  int id = blockIdx.x * 256 + threadIdx.x;  // id = bh*2048 + t
  int n = (id >> 11) & 7;
  int t = id & 2047;
  const bf16* kp = kh + (size_t)id * 128;
  const bf16* rp = rh + ((size_t)(n * 2048 + t)) * 128;
  const float* u1p = u1 + n * 128;
  const float* u2p = u2 + n * 128;
  float s = 0.f;
#pragma unroll
  for (int c0 = 0; c0 < 128; c0 += 8) {
    bf16x8 kv = *(const bf16x8*)(kp + c0);
    bf16x8 rv = *(const bf16x8*)(rp + c0);
#pragma unroll
    for (int j = 0; j < 8; ++j) s += (float)kv[j] * u1p[c0 + j] + (float)rv[j] * u2p[c0 + j];
  }
  uu[id] = s * KSC;
}

// ---------------- flash attention with TXL relative-shift bias (2-phase dbuf pipeline) ----------------
__global__ __launch_bounds__(256, 2) void k_flash(
    const bf16* __restrict__ qh, const bf16* __restrict__ kh,
    const bf16* __restrict__ vht, const bf16* __restrict__ rh,
    const float* __restrict__ uu, bf16* __restrict__ att2)
{
  __shared__ bf16 Ks[2][64 * 128];   // [t][e], chunk-XOR swizzled
  __shared__ bf16 Vs[2][64 * 128];   // [e][t], chunk-XOR swizzled
  __shared__ bf16 QRS[4][16 * 90];   // per-wave: QR window [16][90]; aliased as P [16][64] chunk-XOR

  // strip pairing: blocks x and x+256 land on the same CU (8-XCD round-robin);
  // qb pairs (i, 15-i) -> per-CU tile count constant (49).
  const int x = blockIdx.x;
  const int bh = x & 31;
  const int qb = (x < 256) ? (x >> 5) : (15 - ((x - 256) >> 5));
  const int ib = bh >> 3, nh = bh & 7;
  const int s0 = qb * 64;
  const int tid = threadIdx.x;
  const int w = tid >> 6, lane = tid & 63, g = lane >> 4, c = lane & 15;

  const bf16* qbase = qh + (size_t)bh * 1024 * 128;
  const bf16* kbase = kh + (size_t)bh * 2048 * 128;
  const bf16* vbase = vht + (size_t)bh * 128 * 2048;
  const bf16* rbase = rh + (size_t)nh * 2048 * 128;
  const float* uup  = uu + bh * 2048;

  const int nt = qb + 17;  // keys needed: t <= s0+63+1024

  auto stage = [&](int tile) {
    int pb = tile & 1;
    int t0s = tile * 64;
    char* Kd = (char*)Ks[pb];
    char* Vd = (char*)Vs[pb];
#pragma unroll
    for (int it = 0; it < 4; ++it) {
      int ch = w * 256 + it * 64 + lane;
      int row = ch >> 4, cc2 = ch & 15;
      GLL16(kbase + (size_t)(t0s + row) * 128 + ((cc2 ^ (row & 7)) * 8), Kd + ch * 16);
    }
#pragma unroll
    for (int it = 0; it < 4; ++it) {
      int ch = w * 256 + it * 64 + lane;
      int e = ch >> 3, tc = ch & 7;
      GLL16(vbase + (size_t)e * 2048 + t0s + ((tc ^ (e & 7)) * 8), Vd + ch * 16);
    }
  };

  // Q fragments (prescaled by KSC at projection time)
  bf16x8 qf[4];
  {
    int srow = s0 + 16 * w + c;
#pragma unroll
    for (int kk = 0; kk < 4; ++kk)
      qf[kk] = *(const bf16x8*)(qbase + (size_t)srow * 128 + kk * 32 + g * 8);
  }

  f32x4 Ot[8] = {};
  float m_j[4], l_j[4];
#pragma unroll
  for (int j = 0; j < 4; ++j) { m_j[j] = -1e30f; l_j[j] = 0.f; }

  stage(0);

  for (int tt = 0; tt < nt; ++tt) {
    const int t0 = tt * 64;
    const int pb = tt & 1;
    __syncthreads();               // implicit vmcnt(0) drain: tile tt's K/V are in LDS
    if (tt + 1 < nt) stage(tt + 1);  // prefetch next tile; lands during this tile's compute

    // R fragments straight from global (L2); latency hides under QK
    bf16x8 rf[5][4];
    const int wb = t0 - s0 - 16 * w - 1040 + 4096;
#pragma unroll
    for (int f2 = 0; f2 < 5; ++f2) {
      int u = (wb + 16 * f2 + c) & 2047;
      const bf16* rrow = rbase + (size_t)u * 128;
#pragma unroll
      for (int kk = 0; kk < 4; ++kk) rf[f2][kk] = *(const bf16x8*)(rrow + kk * 32 + g * 8);
    }

    const bf16* Kc = Ks[pb];
    const bf16* Vc = Vs[pb];

    // ---- S = Q K^T ----
    f32x4 sacc[4] = {};
    __builtin_amdgcn_s_setprio(1);
#pragma unroll
    for (int kk = 0; kk < 4; ++kk) {
#pragma unroll
      for (int f = 0; f < 4; ++f) {
        bf16x8 kf = *(const bf16x8*)((const char*)Kc + (16 * f + c) * 256 + (((4 * kk + g) ^ (c & 7)) << 4));
        sacc[f] = MFMA(qf[kk], kf, sacc[f]);
      }
    }
    // ---- bias: QR over the 80-wide u-window ----
    f32x4 bacc[5] = {};
#pragma unroll
    for (int f2 = 0; f2 < 5; ++f2)
#pragma unroll
      for (int kk = 0; kk < 4; ++kk)
        bacc[f2] = MFMA(qf[kk], rf[f2][kk], bacc[f2]);
    __builtin_amdgcn_s_setprio(0);

    // QR -> per-wave LDS (bf16, [16][90]: 4-row bank stride 20 -> ≤2-way)
    bf16* qrw = QRS[w];
#pragma unroll
    for (int f2 = 0; f2 < 5; ++f2)
#pragma unroll
      for (int j = 0; j < 4; ++j)
        qrw[(4 * g + j) * 90 + 16 * f2 + c] = tobf(bacc[f2][j]);

    float uuv[4];
#pragma unroll
    for (int f = 0; f < 4; ++f) uuv[f] = uup[t0 + 16 * f + c];

    // ---- compose scores (bias gather: col = 16f + c - il + 15) ----
    const bool lastT = (tt == nt - 1);
    float zv[4][4];
#pragma unroll
    for (int f = 0; f < 4; ++f) {
#pragma unroll
      for (int j = 0; j < 4; ++j) {
        int il = 4 * g + j;
        float bias = (float)qrw[il * 90 + (16 * f + c - il + 15)];
        float z = sacc[f][j] + bias + uuv[f];
        if (lastT && (16 * f + c > 16 * w + il)) z = -1e30f;
        zv[f][j] = z;
      }
    }
    // ---- online softmax (base 2), rows in 16-lane groups ----
    float alpha[4];
#pragma unroll
    for (int j = 0; j < 4; ++j) {
      float tm = fmaxf(fmaxf(zv[0][j], zv[1][j]), fmaxf(zv[2][j], zv[3][j]));
#pragma unroll
      for (int d = 1; d < 16; d <<= 1) tm = fmaxf(tm, __shfl_xor(tm, d));
      float mn = fmaxf(m_j[j], tm);
      alpha[j] = exp2f(m_j[j] - mn);
      m_j[j] = mn;
      float ps = 0.f;
#pragma unroll
      for (int f = 0; f < 4; ++f) { float pp = exp2f(zv[f][j] - mn); zv[f][j] = pp; ps += pp; }
#pragma unroll
      for (int d = 1; d < 16; d <<= 1) ps += __shfl_xor(ps, d);
      l_j[j] = l_j[j] * alpha[j] + ps;
    }
#pragma unroll
    for (int fo = 0; fo < 8; ++fo)
#pragma unroll
      for (int j = 0; j < 4; ++j) Ot[fo][j] *= alpha[j];

    // ---- P -> LDS (aliases QR buffer; [16][64] with 16B-chunk XOR by row) ----
    bf16* pw = qrw;
#pragma unroll
    for (int f = 0; f < 4; ++f)
#pragma unroll
      for (int j = 0; j < 4; ++j) {
        int il = 4 * g + j;
        pw[il * 64 + ((((2 * f + (c >> 3)) ^ (il & 7)) << 3) | (c & 7))] = tobf(zv[f][j]);
      }

    // ---- O += P V ----
    __builtin_amdgcn_s_setprio(1);
#pragma unroll
    for (int kk2 = 0; kk2 < 2; ++kk2) {
      bf16x8 pa = *(const bf16x8*)(pw + c * 64 + (((4 * kk2 + g) ^ (c & 7)) << 3));
#pragma unroll
      for (int fo = 0; fo < 8; ++fo) {
        int e = 16 * fo + c;
        bf16x8 vf = *(const bf16x8*)((const char*)Vc + e * 128 + (((4 * kk2 + g) ^ (c & 7)) << 4));
        Ot[fo] = MFMA(pa, vf, Ot[fo]);
      }
    }
    __builtin_amdgcn_s_setprio(0);
  }

  // ---- epilogue: divide by l, scatter into att2[b, n*128+s/8, (s%8)*128+e] ----
  bf16* ob = att2 + (size_t)ib * 1024 * 1024;
#pragma unroll
  for (int j = 0; j < 4; ++j) {
    int sg = s0 + 16 * w + 4 * g + j;
    size_t rowb = (size_t)(nh * 128 + (sg >> 3)) * 1024 + ((sg & 7) << 7);
    float inv = 1.f / l_j[j];
#pragma unroll
    for (int fo = 0; fo < 8; ++fo)
      ob[rowb + 16 * fo + c] = tobf(Ot[fo][j] * inv);
  }
}

// ---------------- y = att2 @ w_mlp + x, then LayerNorm ----------------
__global__ __launch_bounds__(256, 2) void k_mlp(
    const bf16* __restrict__ att2, const bf16* __restrict__ wmlp_bt,
    const float* __restrict__ x, const float* __restrict__ lng, const float* __restrict__ lnb,
    float* __restrict__ out)
{
  __shared__ bf16 As[64 * 128];
  __shared__ bf16 Bs[128 * 128];
  const int m0 = blockIdx.x * 64;
  const int tid = threadIdx.x;
  const int w = tid >> 6, lane = tid & 63, g = lane >> 4, c = lane & 15;

  f32x4 acc[8] = {};
  for (int ks = 0; ks < 8; ++ks) {
    int k0 = ks * 128;
    __syncthreads();
#pragma unroll
    for (int it = 0; it < 4; ++it) {
      int ch = w * 256 + it * 64 + lane;
      int row = ch >> 4, cc = ch & 15;
      GLL16(att2 + (size_t)(m0 + row) * 1024 + k0 + ((cc ^ (row & 7)) * 8),
            (char*)As + (w * 256 + it * 64) * 16);
    }
#pragma unroll
    for (int it = 0; it < 8; ++it) {
      int ch = w * 512 + it * 64 + lane;
      int n = ch >> 4, cc = ch & 15;
      GLL16(wmlp_bt + (size_t)n * 1024 + k0 + ((cc ^ (n & 7)) * 8),
            (char*)Bs + (w * 512 + it * 64) * 16);
    }
    __syncthreads();
#pragma unroll
    for (int kk = 0; kk < 4; ++kk) {
      bf16x8 a = *(const bf16x8*)((const char*)As + (16 * w + c) * 256 + (((4 * kk + g) ^ (c & 7)) << 4));
#pragma unroll
      for (int fo = 0; fo < 8; ++fo) {
        bf16x8 b = *(const bf16x8*)((const char*)Bs + (16 * fo + c) * 256 + (((4 * kk + g) ^ (c & 7)) << 4));
        acc[fo] = MFMA(a, b, acc[fo]);
      }
    }
  }
#pragma unroll
  for (int j = 0; j < 4; ++j) {
    int rg = m0 + 16 * w + 4 * g + j;
    float y[8];
    float s1 = 0.f, s2 = 0.f;
#pragma unroll
    for (int fo = 0; fo < 8; ++fo) {
      float v = acc[fo][j] + x[(size_t)rg * 128 + 16 * fo + c];
      y[fo] = v; s1 += v; s2 += v * v;
    }
#pragma unroll
    for (int d = 1; d < 16; d <<= 1) { s1 += __shfl_xor(s1, d); s2 += __shfl_xor(s2, d); }
    float mu = s1 * 0.0078125f;
    float var = s2 * 0.0078125f - mu * mu;
    float rs = rsqrtf(var + 1e-5f);
#pragma unroll
    for (int fo = 0; fo < 8; ++fo) {
      int e = 16 * fo + c;
      out[(size_t)rg * 128 + e] = (y[fo] - mu) * rs * lng[e] + lnb[e];
    }
  }
}

extern "C" void kernel_launch(void* const* d_in, const int* in_sizes, int n_in,
                              void* d_out, int out_size, void* d_ws, size_t ws_size,
                              hipStream_t stream)
{
  const float* x    = (const float*)d_in[0];
  const float* mm   = (const float*)d_in[1];
  const float* u1   = (const float*)d_in[3];
  const float* u2   = (const float*)d_in[4];
  const float* wq   = (const float*)d_in[5];
  const float* wkv  = (const float*)d_in[6];
  const float* wr   = (const float*)d_in[7];
  const float* wmlp = (const float*)d_in[8];
  const float* lng  = (const float*)d_in[9];
  const float* lnb  = (const float*)d_in[10];
  float* out = (float*)d_out;

  char* p = (char*)d_ws;
  bf16* posb    = (bf16*)p;  p += (size_t)262144 * 2;
  bf16* wq_bt   = (bf16*)p;  p += (size_t)131072 * 2;
  bf16* wkv_bt  = (bf16*)p;  p += (size_t)262144 * 2;
  bf16* wr_bt   = (bf16*)p;  p += (size_t)131072 * 2;
  bf16* wmlp_bt = (bf16*)p;  p += (size_t)131072 * 2;
  bf16* xb      = (bf16*)p;  p += (size_t)524288 * 2;
  bf16* memb    = (bf16*)p;  p += (size_t)524288 * 2;
  bf16* qh      = (bf16*)p;  p += (size_t)4 * 8 * 1024 * 128 * 2;
  bf16* kh      = (bf16*)p;  p += (size_t)4 * 8 * 2048 * 128 * 2;
  bf16* vh      = (bf16*)p;  p += (size_t)4 * 8 * 2048 * 128 * 2;
  bf16* vht     = (bf16*)p;  p += (size_t)4 * 8 * 2048 * 128 * 2;
  bf16* rh      = (bf16*)p;  p += (size_t)8 * 2048 * 128 * 2;
  float* uu     = (float*)p; p += (size_t)65536 * 4;
  bf16* att2    = (bf16*)p;  p += (size_t)4 * 1024 * 1024 * 2;

  k_prep<<<dim3(7680), dim3(256), 0, stream>>>(x, mm, wq, wkv, wr, wmlp,
                                               posb, wq_bt, wkv_bt, wr_bt, wmlp_bt, xb, memb);
  k_proj<0><<<dim3(64, 8),   dim3(256), 0, stream>>>(xb,  (const bf16*)nullptr, wq_bt,  qh, (bf16*)nullptr, KSC);
  k_proj<1><<<dim3(128, 16), dim3(256), 0, stream>>>(xb,  memb,                 wkv_bt, kh, vh,             1.0f);
  k_proj<2><<<dim3(32, 8),   dim3(256), 0, stream>>>(posb,(const bf16*)nullptr, wr_bt,  rh, (bf16*)nullptr, 1.0f);
  k_vtrans<<<dim3(32, 2, 32), dim3(256), 0, stream>>>(vh, vht);
  k_uterms<<<dim3(256), dim3(256), 0, stream>>>(kh, rh, u1, u2, uu);
  k_flash<<<dim3(512), dim3(256), 0, stream>>>(qh, kh, vht, rh, uu, att2);
  k_mlp<<<dim3(64), dim3(256), 0, stream>>>(att2, wmlp_bt, x, lng, lnb, out);
}

// Round 3
// 308.823 us; speedup vs baseline: 1.2344x; 1.0309x over previous
//
#include <hip/hip_runtime.h>
#include <hip/hip_bf16.h>
#include <stdint.h>

// Problem constants: B=4, SEG=1024, MEM=1024, TOTAL=2048, D=E=128, H=8
typedef __bf16 bf16;
typedef __attribute__((ext_vector_type(8))) __bf16 bf16x8;
typedef __attribute__((ext_vector_type(4))) __bf16 bf16x4;
typedef __attribute__((ext_vector_type(4))) float f32x4;

#define KSC 0.12764932952880681f  // log2(e)/sqrt(128)

__device__ __forceinline__ f32x4 MFMA(bf16x8 a, bf16x8 b, f32x4 c) {
  return __builtin_amdgcn_mfma_f32_16x16x32_bf16(a, b, c, 0, 0, 0);
}

__device__ __forceinline__ void GLL16(const void* g, void* l) {
  __builtin_amdgcn_global_load_lds(
      (const __attribute__((address_space(1))) void*)g,
      (__attribute__((address_space(3))) void*)l, 16, 0, 0);
}

__device__ __forceinline__ bf16 tobf(float f) { return (bf16)f; }

// ---------------- prep: pos encoding + weight transposes (coalesced READ) + bf16 converts ----------------
__global__ __launch_bounds__(256) void k_prep(
    const float* __restrict__ x, const float* __restrict__ mm,
    const float* __restrict__ wq, const float* __restrict__ wkv,
    const float* __restrict__ wr, const float* __restrict__ wmlp,
    bf16* __restrict__ posb, bf16* __restrict__ wq_bt, bf16* __restrict__ wkv_bt,
    bf16* __restrict__ wr_bt, bf16* __restrict__ wmlp_bt,
    bf16* __restrict__ xb, bf16* __restrict__ memb)
{
  int id = blockIdx.x * 256 + threadIdx.x;
  if (id < 262144) {  // posb[t][j], pos = enc[::-1] -> p = 2047 - t
    int t = id >> 7, j = id & 127;
    float p = (float)(2047 - t);
    float ang = p * exp2f(-(float)j * 0.20762050593046264f);  // 10000^(-j/64)
    float v = ((j & 1) == 0) ? sinf(ang) : cosf(ang);
    posb[id] = tobf(v);
    return;
  }
  id -= 262144;
  if (id < 131072) { int k = id >> 10, n = id & 1023; wq_bt[n * 128 + k] = tobf(wq[id]); return; }
  id -= 131072;
  if (id < 262144) { int k = id >> 11, n = id & 2047; wkv_bt[n * 128 + k] = tobf(wkv[id]); return; }
  id -= 262144;
  if (id < 131072) { int k = id >> 10, n = id & 1023; wr_bt[n * 128 + k] = tobf(wr[id]); return; }
  id -= 131072;
  if (id < 131072) { int k = id >> 7, n = id & 127; wmlp_bt[n * 1024 + k] = tobf(wmlp[id]); return; }
  id -= 131072;
  if (id < 131072) {
    f32x4 v = *(const f32x4*)(x + (size_t)id * 4);
    bf16x4 o; o[0]=tobf(v[0]); o[1]=tobf(v[1]); o[2]=tobf(v[2]); o[3]=tobf(v[3]);
    *(bf16x4*)(xb + (size_t)id * 4) = o;
    return;
  }
  id -= 131072;
  if (id < 131072) {
    f32x4 v = *(const f32x4*)(mm + (size_t)id * 4);
    bf16x4 o; o[0]=tobf(v[0]); o[1]=tobf(v[1]); o[2]=tobf(v[2]); o[3]=tobf(v[3]);
    *(bf16x4*)(memb + (size_t)id * 4) = o;
  }
}

// ---------------- projection GEMM: C[64x128 tile] = A[64x128] * W[128xN], scatter epilogue ----------------
template <int MODE>
__global__ __launch_bounds__(256, 2) void k_proj(
    const bf16* __restrict__ asrc, const bf16* __restrict__ asrc2,
    const bf16* __restrict__ wbt, bf16* __restrict__ out0, bf16* __restrict__ out1,
    float oscale)
{
  __shared__ bf16 As[64 * 128];
  __shared__ bf16 Bs[128 * 128];
  const int m0 = blockIdx.x * 64;
  const int n0 = blockIdx.y * 128;
  const int tid = threadIdx.x;
  const int w = tid >> 6, lane = tid & 63, g = lane >> 4, c = lane & 15;

#pragma unroll
  for (int it = 0; it < 4; ++it) {
    int ch = w * 256 + it * 64 + lane;
    int row = ch >> 4, cc = ch & 15;
    int scc = cc ^ (row & 7);
    const bf16* src;
    if (MODE == 1) {
      int rg = m0 + row;
      int bb = rg >> 11, t = rg & 2047;
      src = (t < 1024) ? (asrc2 + (size_t)(bb * 1024 + t) * 128)
                       : (asrc + (size_t)(bb * 1024 + (t - 1024)) * 128);
    } else {
      src = asrc + (size_t)(m0 + row) * 128;
    }
    GLL16(src + scc * 8, (char*)As + (w * 256 + it * 64) * 16);
  }
#pragma unroll
  for (int it = 0; it < 8; ++it) {
    int ch = w * 512 + it * 64 + lane;
    int n = ch >> 4, cc = ch & 15;
    int scc = cc ^ (n & 7);
    GLL16(wbt + (size_t)(n0 + n) * 128 + scc * 8, (char*)Bs + (w * 512 + it * 64) * 16);
  }
  __syncthreads();

  f32x4 acc[8] = {};
#pragma unroll
  for (int kk = 0; kk < 4; ++kk) {
    bf16x8 a = *(const bf16x8*)((const char*)As + (16 * w + c) * 256 + (((4 * kk + g) ^ (c & 7)) << 4));
#pragma unroll
    for (int fo = 0; fo < 8; ++fo) {
      bf16x8 b = *(const bf16x8*)((const char*)Bs + (16 * fo + c) * 256 + (((4 * kk + g) ^ (c & 7)) << 4));
      acc[fo] = MFMA(a, b, acc[fo]);
    }
  }

#pragma unroll
  for (int fo = 0; fo < 8; ++fo) {
#pragma unroll
    for (int j = 0; j < 4; ++j) {
      int rg = m0 + 16 * w + 4 * g + j;
      int cg = n0 + 16 * fo + c;
      bf16 v = tobf(acc[fo][j] * oscale);
      if (MODE == 0) {
        int b = rg >> 10, s2 = rg & 1023;
        int nn = s2 >> 7;
        int s = ((s2 & 127) << 3) | (cg >> 7);
        int e = cg & 127;
        out0[((size_t)((b * 8 + nn) * 1024 + s)) * 128 + e] = v;
      } else if (MODE == 1) {
        int bb = rg >> 11, t = rg & 2047;
        int nn = (t >> 7) & 7;
        int hlf = (t >> 10) & 1;
        int t2 = ((t & 127) << 4) | (cg >> 7);
        int e = cg & 127;
        if (bb < 2)
          out0[((size_t)(((2 * bb + hlf) * 8 + nn) * 2048 + t2)) * 128 + e] = v;
        else
          out1[((size_t)(((2 * (bb - 2) + hlf) * 8 + nn) * 2048 + t2)) * 128 + e] = v;
      } else {
        int nn = rg >> 8;
        int t = ((rg & 255) << 3) | (cg >> 7);
        int e = cg & 127;
        out0[((size_t)(nn * 2048 + t)) * 128 + e] = v;
      }
    }
  }
}

// ---------------- aux: V transpose (blocks 0..2047) + u-terms (blocks 2048..2303) ----------------
__global__ __launch_bounds__(256) void k_aux(
    const bf16* __restrict__ vh, bf16* __restrict__ vht,
    const bf16* __restrict__ kh, const bf16* __restrict__ rh,
    const float* __restrict__ u1, const float* __restrict__ u2,
    float* __restrict__ uu)
{
  __shared__ bf16 T[64][72];
  const int bid = blockIdx.x;
  if (bid < 2048) {
    int bt = (bid & 31) * 64, be = ((bid >> 5) & 1) * 64, bh = bid >> 6;
    const bf16* src = vh + (size_t)bh * 2048 * 128;
    bf16* dst = vht + (size_t)bh * 128 * 2048;
#pragma unroll
    for (int i2 = 0; i2 < 2; ++i2) {
      int ch = i2 * 256 + threadIdx.x;
      int tt = ch >> 3, cc = ch & 7;
      bf16x8 v = *(const bf16x8*)(src + (size_t)(bt + tt) * 128 + be + cc * 8);
      *(bf16x8*)&T[tt][cc * 8] = v;
    }
    __syncthreads();
#pragma unroll
    for (int i2 = 0; i2 < 2; ++i2) {
      int ch = i2 * 256 + threadIdx.x;
      int ee = ch >> 3, c2 = ch & 7;
      bf16x8 o;
#pragma unroll
      for (int m = 0; m < 8; ++m) o[m] = T[c2 * 8 + m][ee];
      *(bf16x8*)(dst + (size_t)(be + ee) * 2048 + bt + c2 * 8) = o;
    }
  } else {
    int id = (bid - 2048) * 256 + threadIdx.x;  // id = bh*2048 + t
    int n = (id >> 11) & 7;
    int t = id & 2047;
    const bf16* kp = kh + (size_t)id * 128;
    const bf16* rp = rh + ((size_t)(n * 2048 + t)) * 128;
    const float* u1p = u1 + n * 128;
    const float* u2p = u2 + n * 128;
    float s = 0.f;
#pragma unroll
    for (int c0 = 0; c0 < 128; c0 += 8) {
      bf16x8 kv = *(const bf16x8*)(kp + c0);
      bf16x8 rv = *(const bf16x8*)(rp + c0);
#pragma unroll
      for (int j = 0; j < 8; ++j) s += (float)kv[j] * u1p[c0 + j] + (float)rv[j] * u2p[c0 + j];
    }
    uu[id] = s * KSC;
  }
}

// ---------------- flash attention with TXL relative-shift bias ----------------
// Per-tile pipeline: nothing loaded from global is consumed in the same tile.
//   K/V: LDS double-buffer staged one tile ahead (global_load_lds).
//   R:   register pipeline rf[5][4]; window slides 64 = 4 slots; rotate rf[0]<-rf[4],
//        prefetch 4 new slots mid-tile (after QR frees them), consumed next tile.
//   uu:  prefetched into uun[4], swapped at tile end.
__global__ __launch_bounds__(256, 2) void k_flash(
    const bf16* __restrict__ qh, const bf16* __restrict__ kh,
    const bf16* __restrict__ vht, const bf16* __restrict__ rh,
    const float* __restrict__ uu, bf16* __restrict__ att2)
{
  __shared__ bf16 Ks[2][64 * 128];   // [t][e], chunk-XOR swizzled
  __shared__ bf16 Vs[2][64 * 128];   // [e][t], chunk-XOR swizzled
  __shared__ bf16 QRS[4][16 * 90];   // per-wave QR window [16][90]; aliased as P [16][64] chunk-XOR

  // strip pairing: blocks x and x+256 land on the same CU; qb pairs (i,15-i) -> constant 49 tiles/CU.
  const int x = blockIdx.x;
  const int bh = x & 31;
  const int qb = (x < 256) ? (x >> 5) : (15 - ((x - 256) >> 5));
  const int ib = bh >> 3, nh = bh & 7;
  const int s0 = qb * 64;
  const int tid = threadIdx.x;
  const int w = tid >> 6, lane = tid & 63, g = lane >> 4, c = lane & 15;

  const bf16* qbase = qh + (size_t)bh * 1024 * 128;
  const bf16* kbase = kh + (size_t)bh * 2048 * 128;
  const bf16* vbase = vht + (size_t)bh * 128 * 2048;
  const bf16* rbase = rh + (size_t)nh * 2048 * 128;
  const float* uup  = uu + bh * 2048;

  const int nt = qb + 17;  // keys needed: t <= s0+63+1024

  auto stage = [&](int tile) {
    int pb = tile & 1;
    int t0s = tile * 64;
    char* Kd = (char*)Ks[pb];
    char* Vd = (char*)Vs[pb];
#pragma unroll
    for (int it = 0; it < 4; ++it) {
      int ch = w * 256 + it * 64 + lane;
      int row = ch >> 4, cc2 = ch & 15;
      GLL16(kbase + (size_t)(t0s + row) * 128 + ((cc2 ^ (row & 7)) * 8), Kd + ch * 16);
    }
#pragma unroll
    for (int it = 0; it < 4; ++it) {
      int ch = w * 256 + it * 64 + lane;
      int e = ch >> 3, tc = ch & 7;
      GLL16(vbase + (size_t)e * 2048 + t0s + ((tc ^ (e & 7)) * 8), Vd + ch * 16);
    }
  };

  // Q fragments (prescaled by KSC at projection time)
  bf16x8 qf[4];
  {
    int srow = s0 + 16 * w + c;
#pragma unroll
    for (int kk = 0; kk < 4; ++kk)
      qf[kk] = *(const bf16x8*)(qbase + (size_t)srow * 128 + kk * 32 + g * 8);
  }

  // R register pipeline + uu prologue (tile 0)
  bf16x8 rf[5][4];
  float uuv[4], uun[4];
  {
    const int wb0 = -s0 - 16 * w - 1040 + 4096;
#pragma unroll
    for (int f2 = 0; f2 < 5; ++f2) {
      int u = (wb0 + 16 * f2 + c) & 2047;
      const bf16* rrow = rbase + (size_t)u * 128;
#pragma unroll
      for (int kk = 0; kk < 4; ++kk) rf[f2][kk] = *(const bf16x8*)(rrow + kk * 32 + g * 8);
    }
#pragma unroll
    for (int f = 0; f < 4; ++f) uuv[f] = uup[16 * f + c];
  }

  f32x4 Ot[8] = {};
  float m_j[4], l_j[4];
#pragma unroll
  for (int j = 0; j < 4; ++j) { m_j[j] = -1e30f; l_j[j] = 0.f; }

  stage(0);

  for (int tt = 0; tt < nt; ++tt) {
    const int pb = tt & 1;
    const bool notlast = (tt + 1 < nt);
    __syncthreads();               // stage(tt) + prefetches from tile tt-1 have landed
    if (notlast) stage(tt + 1);

    const bf16* Kc = Ks[pb];
    const bf16* Vc = Vs[pb];

    // ---- S = Q K^T ----
    f32x4 sacc[4] = {};
    __builtin_amdgcn_s_setprio(1);
#pragma unroll
    for (int kk = 0; kk < 4; ++kk) {
#pragma unroll
      for (int f = 0; f < 4; ++f) {
        bf16x8 kf = *(const bf16x8*)((const char*)Kc + (16 * f + c) * 256 + (((4 * kk + g) ^ (c & 7)) << 4));
        sacc[f] = MFMA(qf[kk], kf, sacc[f]);
      }
    }
    // ---- bias: QR over the 80-wide u-window (fragments already in registers) ----
    f32x4 bacc[5] = {};
#pragma unroll
    for (int f2 = 0; f2 < 5; ++f2)
#pragma unroll
      for (int kk = 0; kk < 4; ++kk)
        bacc[f2] = MFMA(qf[kk], rf[f2][kk], bacc[f2]);
    __builtin_amdgcn_s_setprio(0);

    // QR -> per-wave LDS
    bf16* qrw = QRS[w];
#pragma unroll
    for (int f2 = 0; f2 < 5; ++f2)
#pragma unroll
      for (int j = 0; j < 4; ++j)
        qrw[(4 * g + j) * 90 + 16 * f2 + c] = tobf(bacc[f2][j]);

    // ---- rotate + prefetch R fragments and uu for tile tt+1 (consumed NEXT tile) ----
    if (notlast) {
#pragma unroll
      for (int kk = 0; kk < 4; ++kk) rf[0][kk] = rf[4][kk];
      const int wbn = 64 * (tt + 1) - s0 - 16 * w - 1040 + 4096;
#pragma unroll
      for (int f2 = 1; f2 < 5; ++f2) {
        int u = (wbn + 16 * f2 + c) & 2047;
        const bf16* rrow = rbase + (size_t)u * 128;
#pragma unroll
        for (int kk = 0; kk < 4; ++kk) rf[f2][kk] = *(const bf16x8*)(rrow + kk * 32 + g * 8);
      }
#pragma unroll
      for (int f = 0; f < 4; ++f) uun[f] = uup[64 * (tt + 1) + 16 * f + c];
    }

    // ---- compose scores (bias gather: col = 16f + c - il + 15) ----
    const bool lastT = !notlast;
    float zv[4][4];
#pragma unroll
    for (int f = 0; f < 4; ++f) {
#pragma unroll
      for (int j = 0; j < 4; ++j) {
        int il = 4 * g + j;
        float bias = (float)qrw[il * 90 + (16 * f + c - il + 15)];
        float z = sacc[f][j] + bias + uuv[f];
        if (lastT && (16 * f + c > 16 * w + il)) z = -1e30f;
        zv[f][j] = z;
      }
    }
    // ---- online softmax (base 2), d-outer so the 4 independent j-chains interleave ----
    float tm[4], ps[4], alpha[4];
#pragma unroll
    for (int j = 0; j < 4; ++j)
      tm[j] = fmaxf(fmaxf(zv[0][j], zv[1][j]), fmaxf(zv[2][j], zv[3][j]));
#pragma unroll
    for (int d = 1; d < 16; d <<= 1)
#pragma unroll
      for (int j = 0; j < 4; ++j) tm[j] = fmaxf(tm[j], __shfl_xor(tm[j], d));
#pragma unroll
    for (int j = 0; j < 4; ++j) {
      float mn = fmaxf(m_j[j], tm[j]);
      alpha[j] = exp2f(m_j[j] - mn);
      m_j[j] = mn;
    }
#pragma unroll
    for (int j = 0; j < 4; ++j) {
      ps[j] = 0.f;
#pragma unroll
      for (int f = 0; f < 4; ++f) { float pp = exp2f(zv[f][j] - m_j[j]); zv[f][j] = pp; ps[j] += pp; }
    }
#pragma unroll
    for (int d = 1; d < 16; d <<= 1)
#pragma unroll
      for (int j = 0; j < 4; ++j) ps[j] += __shfl_xor(ps[j], d);
#pragma unroll
    for (int j = 0; j < 4; ++j) l_j[j] = l_j[j] * alpha[j] + ps[j];
#pragma unroll
    for (int fo = 0; fo < 8; ++fo)
#pragma unroll
      for (int j = 0; j < 4; ++j) Ot[fo][j] *= alpha[j];

    // ---- P -> LDS (aliases QR buffer; [16][64] with 16B-chunk XOR by row) ----
    bf16* pw = qrw;
#pragma unroll
    for (int f = 0; f < 4; ++f)
#pragma unroll
      for (int j = 0; j < 4; ++j) {
        int il = 4 * g + j;
        pw[il * 64 + ((((2 * f + (c >> 3)) ^ (il & 7)) << 3) | (c & 7))] = tobf(zv[f][j]);
      }

    // ---- O += P V ----
    __builtin_amdgcn_s_setprio(1);
#pragma unroll
    for (int kk2 = 0; kk2 < 2; ++kk2) {
      bf16x8 pa = *(const bf16x8*)(pw + c * 64 + (((4 * kk2 + g) ^ (c & 7)) << 3));
#pragma unroll
      for (int fo = 0; fo < 8; ++fo) {
        int e = 16 * fo + c;
        bf16x8 vf = *(const bf16x8*)((const char*)Vc + e * 128 + (((4 * kk2 + g) ^ (c & 7)) << 4));
        Ot[fo] = MFMA(pa, vf, Ot[fo]);
      }
    }
    __builtin_amdgcn_s_setprio(0);

#pragma unroll
    for (int f = 0; f < 4; ++f) uuv[f] = uun[f];
  }

  // ---- epilogue: divide by l, scatter into att2[b, n*128+s/8, (s%8)*128+e] ----
  bf16* ob = att2 + (size_t)ib * 1024 * 1024;
#pragma unroll
  for (int j = 0; j < 4; ++j) {
    int sg = s0 + 16 * w + 4 * g + j;
    size_t rowb = (size_t)(nh * 128 + (sg >> 3)) * 1024 + ((sg & 7) << 7);
    float inv = 1.f / l_j[j];
#pragma unroll
    for (int fo = 0; fo < 8; ++fo)
      ob[rowb + 16 * fo + c] = tobf(Ot[fo][j] * inv);
  }
}

// ---------------- y = att2 @ w_mlp + x, then LayerNorm ----------------
__global__ __launch_bounds__(256, 2) void k_mlp(
    const bf16* __restrict__ att2, const bf16* __restrict__ wmlp_bt,
    const float* __restrict__ x, const float* __restrict__ lng, const float* __restrict__ lnb,
    float* __restrict__ out)
{
  __shared__ bf16 As[64 * 128];
  __shared__ bf16 Bs[128 * 128];
  const int m0 = blockIdx.x * 64;
  const int tid = threadIdx.x;
  const int w = tid >> 6, lane = tid & 63, g = lane >> 4, c = lane & 15;

  f32x4 acc[8] = {};
  for (int ks = 0; ks < 8; ++ks) {
    int k0 = ks * 128;
    __syncthreads();
#pragma unroll
    for (int it = 0; it < 4; ++it) {
      int ch = w * 256 + it * 64 + lane;
      int row = ch >> 4, cc = ch & 15;
      GLL16(att2 + (size_t)(m0 + row) * 1024 + k0 + ((cc ^ (row & 7)) * 8),
            (char*)As + (w * 256 + it * 64) * 16);
    }
#pragma unroll
    for (int it = 0; it < 8; ++it) {
      int ch = w * 512 + it * 64 + lane;
      int n = ch >> 4, cc = ch & 15;
      GLL16(wmlp_bt + (size_t)n * 1024 + k0 + ((cc ^ (n & 7)) * 8),
            (char*)Bs + (w * 512 + it * 64) * 16);
    }
    __syncthreads();
#pragma unroll
    for (int kk = 0; kk < 4; ++kk) {
      bf16x8 a = *(const bf16x8*)((const char*)As + (16 * w + c) * 256 + (((4 * kk + g) ^ (c & 7)) << 4));
#pragma unroll
      for (int fo = 0; fo < 8; ++fo) {
        bf16x8 b = *(const bf16x8*)((const char*)Bs + (16 * fo + c) * 256 + (((4 * kk + g) ^ (c & 7)) << 4));
        acc[fo] = MFMA(a, b, acc[fo]);
      }
    }
  }
#pragma unroll
  for (int j = 0; j < 4; ++j) {
    int rg = m0 + 16 * w + 4 * g + j;
    float y[8];
    float s1 = 0.f, s2 = 0.f;
#pragma unroll
    for (int fo = 0; fo < 8; ++fo) {
      float v = acc[fo][j] + x[(size_t)rg * 128 + 16 * fo + c];
      y[fo] = v; s1 += v; s2 += v * v;
    }
#pragma unroll
    for (int d = 1; d < 16; d <<= 1) { s1 += __shfl_xor(s1, d); s2 += __shfl_xor(s2, d); }
    float mu = s1 * 0.0078125f;
    float var = s2 * 0.0078125f - mu * mu;
    float rs = rsqrtf(var + 1e-5f);
#pragma unroll
    for (int fo = 0; fo < 8; ++fo) {
      int e = 16 * fo + c;
      out[(size_t)rg * 128 + e] = (y[fo] - mu) * rs * lng[e] + lnb[e];
    }
  }
}

extern "C" void kernel_launch(void* const* d_in, const int* in_sizes, int n_in,
                              void* d_out, int out_size, void* d_ws, size_t ws_size,
                              hipStream_t stream)
{
  const float* x    = (const float*)d_in[0];
  const float* mm   = (const float*)d_in[1];
  const float* u1   = (const float*)d_in[3];
  const float* u2   = (const float*)d_in[4];
  const float* wq   = (const float*)d_in[5];
  const float* wkv  = (const float*)d_in[6];
  const float* wr   = (const float*)d_in[7];
  const float* wmlp = (const float*)d_in[8];
  const float* lng  = (const float*)d_in[9];
  const float* lnb  = (const float*)d_in[10];
  float* out = (float*)d_out;

  char* p = (char*)d_ws;
  bf16* posb    = (bf16*)p;  p += (size_t)262144 * 2;
  bf16* wq_bt   = (bf16*)p;  p += (size_t)131072 * 2;
  bf16* wkv_bt  = (bf16*)p;  p += (size_t)262144 * 2;
  bf16* wr_bt   = (bf16*)p;  p += (size_t)131072 * 2;
  bf16* wmlp_bt = (bf16*)p;  p += (size_t)131072 * 2;
  bf16* xb      = (bf16*)p;  p += (size_t)524288 * 2;
  bf16* memb    = (bf16*)p;  p += (size_t)524288 * 2;
  bf16* qh      = (bf16*)p;  p += (size_t)4 * 8 * 1024 * 128 * 2;
  bf16* kh      = (bf16*)p;  p += (size_t)4 * 8 * 2048 * 128 * 2;
  bf16* vh      = (bf16*)p;  p += (size_t)4 * 8 * 2048 * 128 * 2;
  bf16* vht     = (bf16*)p;  p += (size_t)4 * 8 * 2048 * 128 * 2;
  bf16* rh      = (bf16*)p;  p += (size_t)8 * 2048 * 128 * 2;
  float* uu     = (float*)p; p += (size_t)65536 * 4;
  bf16* att2    = (bf16*)p;  p += (size_t)4 * 1024 * 1024 * 2;

  k_prep<<<dim3(4608), dim3(256), 0, stream>>>(x, mm, wq, wkv, wr, wmlp,
                                               posb, wq_bt, wkv_bt, wr_bt, wmlp_bt, xb, memb);
  k_proj<0><<<dim3(64, 8),   dim3(256), 0, stream>>>(xb,  (const bf16*)nullptr, wq_bt,  qh, (bf16*)nullptr, KSC);
  k_proj<1><<<dim3(128, 16), dim3(256), 0, stream>>>(xb,  memb,                 wkv_bt, kh, vh,             1.0f);
  k_proj<2><<<dim3(32, 8),   dim3(256), 0, stream>>>(posb,(const bf16*)nullptr, wr_bt,  rh, (bf16*)nullptr, 1.0f);
  k_aux<<<dim3(2304), dim3(256), 0, stream>>>(vh, vht, kh, rh, u1, u2, uu);
  k_flash<<<dim3(512), dim3(256), 0, stream>>>(qh, kh, vht, rh, uu, att2);
  k_mlp<<<dim3(64), dim3(256), 0, stream>>>(att2, wmlp_bt, x, lng, lnb, out);
}

// Round 4
// 273.885 us; speedup vs baseline: 1.3918x; 1.1276x over previous
//
#include <hip/hip_runtime.h>
#include <hip/hip_bf16.h>
#include <stdint.h>

// Problem constants: B=4, SEG=1024, MEM=1024, TOTAL=2048, D=E=128, H=8
typedef __bf16 bf16;
typedef __attribute__((ext_vector_type(8))) __bf16 bf16x8;
typedef __attribute__((ext_vector_type(4))) __bf16 bf16x4;
typedef __attribute__((ext_vector_type(4))) float f32x4;

#define KSC 0.12764932952880681f  // log2(e)/sqrt(128)

__device__ __forceinline__ f32x4 MFMA(bf16x8 a, bf16x8 b, f32x4 c) {
  return __builtin_amdgcn_mfma_f32_16x16x32_bf16(a, b, c, 0, 0, 0);
}

__device__ __forceinline__ void GLL16(const void* g, void* l) {
  __builtin_amdgcn_global_load_lds(
      (const __attribute__((address_space(1))) void*)g,
      (__attribute__((address_space(3))) void*)l, 16, 0, 0);
}

__device__ __forceinline__ bf16 tobf(float f) { return (bf16)f; }

// ---------------- prep: pos encoding + weight transposes (coalesced READ) + bf16 converts ----------------
__global__ __launch_bounds__(256) void k_prep(
    const float* __restrict__ x, const float* __restrict__ mm,
    const float* __restrict__ wq, const float* __restrict__ wkv,
    const float* __restrict__ wr, const float* __restrict__ wmlp,
    bf16* __restrict__ posb, bf16* __restrict__ wq_bt, bf16* __restrict__ wkv_bt,
    bf16* __restrict__ wr_bt, bf16* __restrict__ wmlp_bt,
    bf16* __restrict__ xb, bf16* __restrict__ memb)
{
  int id = blockIdx.x * 256 + threadIdx.x;
  if (id < 262144) {  // posb[t][j], pos = enc[::-1] -> p = 2047 - t
    int t = id >> 7, j = id & 127;
    float p = (float)(2047 - t);
    float ang = p * exp2f(-(float)j * 0.20762050593046264f);  // 10000^(-j/64)
    float v = ((j & 1) == 0) ? sinf(ang) : cosf(ang);
    posb[id] = tobf(v);
    return;
  }
  id -= 262144;
  if (id < 131072) { int k = id >> 10, n = id & 1023; wq_bt[n * 128 + k] = tobf(wq[id]); return; }
  id -= 131072;
  if (id < 262144) { int k = id >> 11, n = id & 2047; wkv_bt[n * 128 + k] = tobf(wkv[id]); return; }
  id -= 262144;
  if (id < 131072) { int k = id >> 10, n = id & 1023; wr_bt[n * 128 + k] = tobf(wr[id]); return; }
  id -= 131072;
  if (id < 131072) { int k = id >> 7, n = id & 127; wmlp_bt[n * 1024 + k] = tobf(wmlp[id]); return; }
  id -= 131072;
  if (id < 131072) {
    f32x4 v = *(const f32x4*)(x + (size_t)id * 4);
    bf16x4 o; o[0]=tobf(v[0]); o[1]=tobf(v[1]); o[2]=tobf(v[2]); o[3]=tobf(v[3]);
    *(bf16x4*)(xb + (size_t)id * 4) = o;
    return;
  }
  id -= 131072;
  if (id < 131072) {
    f32x4 v = *(const f32x4*)(mm + (size_t)id * 4);
    bf16x4 o; o[0]=tobf(v[0]); o[1]=tobf(v[1]); o[2]=tobf(v[2]); o[3]=tobf(v[3]);
    *(bf16x4*)(memb + (size_t)id * 4) = o;
  }
}

// ---------------- projection GEMM: C[64x128 tile] = A[64x128] * W[128xN], scatter epilogue ----------------
// MODE 0: Q-proj -> out0 = (q+u1)*KSC, out1 = (q+u2)*KSC
// MODE 1: KV-proj -> out0 = k, out1 = v
// MODE 2: R-proj -> out0 = r (rows [0,2112): row t also mirrored at 2048+t for t<64)
template <int MODE>
__global__ __launch_bounds__(256, 2) void k_proj(
    const bf16* __restrict__ asrc, const bf16* __restrict__ asrc2,
    const bf16* __restrict__ wbt, bf16* __restrict__ out0, bf16* __restrict__ out1,
    const float* __restrict__ u1, const float* __restrict__ u2)
{
  __shared__ bf16 As[64 * 128];
  __shared__ bf16 Bs[128 * 128];
  const int m0 = blockIdx.x * 64;
  const int n0 = blockIdx.y * 128;
  const int tid = threadIdx.x;
  const int w = tid >> 6, lane = tid & 63, g = lane >> 4, c = lane & 15;

#pragma unroll
  for (int it = 0; it < 4; ++it) {
    int ch = w * 256 + it * 64 + lane;
    int row = ch >> 4, cc = ch & 15;
    int scc = cc ^ (row & 7);
    const bf16* src;
    if (MODE == 1) {
      int rg = m0 + row;
      int bb = rg >> 11, t = rg & 2047;
      src = (t < 1024) ? (asrc2 + (size_t)(bb * 1024 + t) * 128)
                       : (asrc + (size_t)(bb * 1024 + (t - 1024)) * 128);
    } else {
      src = asrc + (size_t)(m0 + row) * 128;
    }
    GLL16(src + scc * 8, (char*)As + (w * 256 + it * 64) * 16);
  }
#pragma unroll
  for (int it = 0; it < 8; ++it) {
    int ch = w * 512 + it * 64 + lane;
    int n = ch >> 4, cc = ch & 15;
    int scc = cc ^ (n & 7);
    GLL16(wbt + (size_t)(n0 + n) * 128 + scc * 8, (char*)Bs + (w * 512 + it * 64) * 16);
  }
  __syncthreads();

  f32x4 acc[8] = {};
#pragma unroll
  for (int kk = 0; kk < 4; ++kk) {
    bf16x8 a = *(const bf16x8*)((const char*)As + (16 * w + c) * 256 + (((4 * kk + g) ^ (c & 7)) << 4));
#pragma unroll
    for (int fo = 0; fo < 8; ++fo) {
      bf16x8 b = *(const bf16x8*)((const char*)Bs + (16 * fo + c) * 256 + (((4 * kk + g) ^ (c & 7)) << 4));
      acc[fo] = MFMA(a, b, acc[fo]);
    }
  }

#pragma unroll
  for (int fo = 0; fo < 8; ++fo) {
#pragma unroll
    for (int j = 0; j < 4; ++j) {
      int rg = m0 + 16 * w + 4 * g + j;
      int cg = n0 + 16 * fo + c;
      float av = acc[fo][j];
      if (MODE == 0) {
        int b = rg >> 10, s2 = rg & 1023;
        int nn = s2 >> 7;
        int s = ((s2 & 127) << 3) | (cg >> 7);
        int e = cg & 127;
        size_t idx = ((size_t)((b * 8 + nn) * 1024 + s)) * 128 + e;
        out0[idx] = tobf((av + u1[nn * 128 + e]) * KSC);
        out1[idx] = tobf((av + u2[nn * 128 + e]) * KSC);
      } else if (MODE == 1) {
        int bb = rg >> 11, t = rg & 2047;
        int nn = (t >> 7) & 7;
        int hlf = (t >> 10) & 1;
        int t2 = ((t & 127) << 4) | (cg >> 7);
        int e = cg & 127;
        bf16 v = tobf(av);
        if (bb < 2)
          out0[((size_t)(((2 * bb + hlf) * 8 + nn) * 2048 + t2)) * 128 + e] = v;
        else
          out1[((size_t)(((2 * (bb - 2) + hlf) * 8 + nn) * 2048 + t2)) * 128 + e] = v;
      } else {
        int nn = rg >> 8;
        int t = ((rg & 255) << 3) | (cg >> 7);
        int e = cg & 127;
        bf16 v = tobf(av);
        out0[((size_t)(nn * 2112 + t)) * 128 + e] = v;
        if (t < 64) out0[((size_t)(nn * 2112 + 2048 + t)) * 128 + e] = v;  // wrap extension
      }
    }
  }
}

// ---------------- V transpose: vh[bh][t][e] -> vht[bh][e][t] ----------------
__global__ __launch_bounds__(256) void k_vtrans(const bf16* __restrict__ vh, bf16* __restrict__ vht)
{
  __shared__ bf16 T[64][72];
  int bt = blockIdx.x * 64, be = blockIdx.y * 64, bh = blockIdx.z;
  const bf16* src = vh + (size_t)bh * 2048 * 128;
  bf16* dst = vht + (size_t)bh * 128 * 2048;
#pragma unroll
  for (int i2 = 0; i2 < 2; ++i2) {
    int ch = i2 * 256 + threadIdx.x;
    int tt = ch >> 3, cc = ch & 7;
    bf16x8 v = *(const bf16x8*)(src + (size_t)(bt + tt) * 128 + be + cc * 8);
    *(bf16x8*)&T[tt][cc * 8] = v;
  }
  __syncthreads();
#pragma unroll
  for (int i2 = 0; i2 < 2; ++i2) {
    int ch = i2 * 256 + threadIdx.x;
    int ee = ch >> 3, c2 = ch & 7;
    bf16x8 o;
#pragma unroll
    for (int m = 0; m < 8; ++m) o[m] = T[c2 * 8 + m][ee];
    *(bf16x8*)(dst + (size_t)(be + ee) * 2048 + bt + c2 * 8) = o;
  }
}

// ---------------- flash attention, swapped-operand layout (lane owns score row s=c) ----------------
// S^T = mfma(K, Qk), QR^T = mfma(R, Qr); u1/u2 pre-folded into Qk/Qr; defer-max rescale.
__global__ __launch_bounds__(256, 2) void k_flash(
    const bf16* __restrict__ qhk, const bf16* __restrict__ qhr,
    const bf16* __restrict__ kh, const bf16* __restrict__ vht,
    const bf16* __restrict__ rhe, bf16* __restrict__ att2)
{
  __shared__ bf16 Ks[2][64 * 128];   // [t][e], chunk-XOR swizzled
  __shared__ bf16 Vs[2][64 * 128];   // [e][t], chunk-XOR swizzled
  __shared__ char QRS[4][2688];      // per-wave: qr [16 rows x stride 82 bf16]; P aliased [16 x stride 80 bf16]

  const int x = blockIdx.x;
  const int bh = x & 31;
  const int qb = (x < 256) ? (x >> 5) : (15 - ((x - 256) >> 5));
  const int ib = bh >> 3, nh = bh & 7;
  const int s0 = qb * 64;
  const int tid = threadIdx.x;
  const int w = tid >> 6, lane = tid & 63, g = lane >> 4, c = lane & 15;

  const bf16* qkb  = qhk + (size_t)bh * 1024 * 128;
  const bf16* qrb  = qhr + (size_t)bh * 1024 * 128;
  const bf16* kbase = kh + (size_t)bh * 2048 * 128;
  const bf16* vbase = vht + (size_t)bh * 128 * 2048;
  const bf16* rbase = rhe + (size_t)nh * 2112 * 128;

  const int nt = qb + 17;  // keys needed: t <= s0+63+1024

  // ---- strength-reduced stage pointers (advance by constants per tile) ----
  const bf16 *kp0, *kp1, *vp0, *vp1, *vp2, *vp3;
  {
    int ch0 = w * 256 + lane;
    int ch1 = ch0 + 64;
    int r0 = ch0 >> 4, cc0 = ch0 & 15;
    int r1 = ch1 >> 4, cc1 = ch1 & 15;
    kp0 = kbase + (size_t)r0 * 128 + (cc0 ^ (r0 & 7)) * 8;
    kp1 = kbase + (size_t)r1 * 128 + (cc1 ^ (r1 & 7)) * 8;
    int e0 = ch0 >> 3, t0c = ch0 & 7;
    int e1 = ch1 >> 3, t1c = ch1 & 7;
    int e2 = e0 + 16, e3 = e1 + 16;  // ch + 128 => e + 16, same &7
    vp0 = vbase + (size_t)e0 * 2048 + (t0c ^ (e0 & 7)) * 8;
    vp1 = vbase + (size_t)e1 * 2048 + (t1c ^ (e1 & 7)) * 8;
    vp2 = vbase + (size_t)e2 * 2048 + (t0c ^ (e2 & 7)) * 8;
    vp3 = vbase + (size_t)e3 * 2048 + (t1c ^ (e3 & 7)) * 8;
  }
  const int dof = (w * 256 + lane) * 16;  // LDS dest byte offset, chunk it=0

  auto stage = [&](char* Kd, char* Vd) {
    GLL16(kp0, Kd + dof);
    GLL16(kp1, Kd + dof + 1024);
    GLL16(kp0 + 1024, Kd + dof + 2048);   // rows +8: same swizzle
    GLL16(kp1 + 1024, Kd + dof + 3072);
    GLL16(vp0, Vd + dof);
    GLL16(vp1, Vd + dof + 1024);
    GLL16(vp2, Vd + dof + 2048);
    GLL16(vp3, Vd + dof + 3072);
    kp0 += 8192; kp1 += 8192;
    vp0 += 64; vp1 += 64; vp2 += 64; vp3 += 64;
  };

  // ---- Q fragments (both variants; serve as MFMA B-operands) ----
  bf16x8 qfK[4], qfR[4];
  {
    int srow = s0 + 16 * w + c;
#pragma unroll
    for (int kk = 0; kk < 4; ++kk) {
      qfK[kk] = *(const bf16x8*)(qkb + (size_t)srow * 128 + kk * 32 + g * 8);
      qfR[kk] = *(const bf16x8*)(qrb + (size_t)srow * 128 + kk * 32 + g * 8);
    }
  }

  // ---- R register pipeline: rhe is mod-free (2112 rows); 5 per-lane pointers ----
  bf16x8 rf[5][4];
  const bf16* rp[5];
  {
    const int L0 = 1008 - s0 - 16 * w + c;  // >= 0 for all blocks/waves
#pragma unroll
    for (int f2 = 0; f2 < 5; ++f2) {
      rp[f2] = rbase + (size_t)(L0 + 16 * f2) * 128 + g * 8;
#pragma unroll
      for (int kk = 0; kk < 4; ++kk) rf[f2][kk] = *(const bf16x8*)(rp[f2] + kk * 32);
      rp[f2] += 64 * 128;
    }
  }

  f32x4 Ot[8] = {};
  float m_r = -1e30f, l_r = 0.f;  // per-lane: row s = c

  stage((char*)Ks[0], (char*)Vs[0]);

  for (int tt = 0; tt < nt; ++tt) {
    __syncthreads();   // implicit vmcnt(0): tile tt K/V in LDS; rf(tt) regs ready
    const bool notlast = (tt + 1 < nt);
    if (notlast) stage((char*)Ks[(tt + 1) & 1], (char*)Vs[(tt + 1) & 1]);

    const bf16* Kc = Ks[tt & 1];
    const bf16* Vc = Vs[tt & 1];

    // ---- S^T = K Q^T : sacc[f][j] = S[s=c][t = 16f+4g+j] ----
    f32x4 sacc[4] = {};
    __builtin_amdgcn_s_setprio(1);
#pragma unroll
    for (int kk = 0; kk < 4; ++kk) {
#pragma unroll
      for (int f = 0; f < 4; ++f) {
        bf16x8 kf = *(const bf16x8*)((const char*)Kc + (16 * f + c) * 256 + (((4 * kk + g) ^ (c & 7)) << 4));
        sacc[f] = MFMA(kf, qfK[kk], sacc[f]);
      }
    }
    // ---- QR^T: bacc[f2][j] = QR[s=c][W = 16f2+4g+j] ----
    f32x4 bacc[5] = {};
#pragma unroll
    for (int f2 = 0; f2 < 5; ++f2)
#pragma unroll
      for (int kk = 0; kk < 4; ++kk)
        bacc[f2] = MFMA(rf[f2][kk], qfR[kk], bacc[f2]);
    __builtin_amdgcn_s_setprio(0);

    // ---- qr -> per-wave LDS [s=c][W], stride 82 ----
    bf16* qrw = (bf16*)QRS[w];
#pragma unroll
    for (int f2 = 0; f2 < 5; ++f2)
#pragma unroll
      for (int j = 0; j < 4; ++j)
        qrw[c * 82 + 16 * f2 + 4 * g + j] = tobf(bacc[f2][j]);

    // ---- prefetch R fragments for tile tt+1 (consumed next tile) ----
    if (notlast) {
#pragma unroll
      for (int f2 = 0; f2 < 5; ++f2) {
#pragma unroll
        for (int kk = 0; kk < 4; ++kk) rf[f2][kk] = *(const bf16x8*)(rp[f2] + kk * 32);
        rp[f2] += 64 * 128;
      }
    }

    // ---- compose scores: z[f][j] = S + bias(W = t_local - c + 15); mask last tile ----
    float zv[4][4];
#pragma unroll
    for (int f = 0; f < 4; ++f)
#pragma unroll
      for (int j = 0; j < 4; ++j) {
        int tl = 16 * f + 4 * g + j;
        float z = sacc[f][j] + (float)qrw[c * 82 + (tl - c + 15)];
        if (!notlast && (tl > 16 * w + c)) z = -1e30f;
        zv[f][j] = z;
      }

    // ---- online softmax: lane owns row c; in-lane reduce + 2 shuffles ----
    float pm = fmaxf(fmaxf(fmaxf(zv[0][0], zv[0][1]), fmaxf(zv[0][2], zv[0][3])),
                     fmaxf(fmaxf(zv[1][0], zv[1][1]), fmaxf(zv[1][2], zv[1][3])));
    float pm2 = fmaxf(fmaxf(fmaxf(zv[2][0], zv[2][1]), fmaxf(zv[2][2], zv[2][3])),
                      fmaxf(fmaxf(zv[3][0], zv[3][1]), fmaxf(zv[3][2], zv[3][3])));
    pm = fmaxf(pm, pm2);
    pm = fmaxf(pm, __shfl_xor(pm, 16));
    pm = fmaxf(pm, __shfl_xor(pm, 32));

    float alpha = 1.f;
    if (!__all(pm <= m_r + 8.0f)) {   // rescale (rare after tile 0)
      float mn = fmaxf(m_r, pm);
      alpha = exp2f(m_r - mn);
      m_r = mn;
      float at[4];
#pragma unroll
      for (int j = 0; j < 4; ++j) at[j] = __shfl(alpha, 20 * g + j);
#pragma unroll
      for (int fo = 0; fo < 8; ++fo)
#pragma unroll
        for (int j = 0; j < 4; ++j) Ot[fo][j] *= at[j];
    }

    float ps = 0.f;
#pragma unroll
    for (int f = 0; f < 4; ++f)
#pragma unroll
      for (int j = 0; j < 4; ++j) { float pp = exp2f(zv[f][j] - m_r); zv[f][j] = pp; ps += pp; }
    ps += __shfl_xor(ps, 16);
    ps += __shfl_xor(ps, 32);
    l_r = l_r * alpha + ps;

    // ---- P -> LDS [s=c][t], granule-XOR for conflict-free b128 reads ----
    bf16* pw = (bf16*)QRS[w];
#pragma unroll
    for (int f = 0; f < 4; ++f)
#pragma unroll
      for (int j = 0; j < 4; ++j) {
        int t = 16 * f + 4 * g + j;
        pw[c * 80 + ((((t >> 3) ^ (c & 7)) << 3) | (t & 7))] = tobf(zv[f][j]);
      }

    // ---- O += P V ----
    __builtin_amdgcn_s_setprio(1);
#pragma unroll
    for (int kk2 = 0; kk2 < 2; ++kk2) {
      bf16x8 pa = *(const bf16x8*)(pw + c * 80 + (((4 * kk2 + g) ^ (c & 7)) << 3));
#pragma unroll
      for (int fo = 0; fo < 8; ++fo) {
        int e = 16 * fo + c;
        bf16x8 vf = *(const bf16x8*)((const char*)Vc + e * 128 + (((4 * kk2 + g) ^ (c & 7)) << 4));
        Ot[fo] = MFMA(pa, vf, Ot[fo]);
      }
    }
    __builtin_amdgcn_s_setprio(0);
  }

  // ---- epilogue: transpose l to row space (rows = 4g+j), divide, scatter ----
  float linv[4];
#pragma unroll
  for (int j = 0; j < 4; ++j) linv[j] = 1.f / __shfl(l_r, 20 * g + j);
  bf16* ob = att2 + (size_t)ib * 1024 * 1024;
#pragma unroll
  for (int j = 0; j < 4; ++j) {
    int sg = s0 + 16 * w + 4 * g + j;
    size_t rowb = (size_t)(nh * 128 + (sg >> 3)) * 1024 + ((sg & 7) << 7);
#pragma unroll
    for (int fo = 0; fo < 8; ++fo)
      ob[rowb + 16 * fo + c] = tobf(Ot[fo][j] * linv[j]);
  }
}

// ---------------- y = att2 @ w_mlp + x, then LayerNorm ----------------
__global__ __launch_bounds__(256, 2) void k_mlp(
    const bf16* __restrict__ att2, const bf16* __restrict__ wmlp_bt,
    const float* __restrict__ x, const float* __restrict__ lng, const float* __restrict__ lnb,
    float* __restrict__ out)
{
  __shared__ bf16 As[64 * 128];
  __shared__ bf16 Bs[128 * 128];
  const int m0 = blockIdx.x * 64;
  const int tid = threadIdx.x;
  const int w = tid >> 6, lane = tid & 63, g = lane >> 4, c = lane & 15;

  f32x4 acc[8] = {};
  for (int ks = 0; ks < 8; ++ks) {
    int k0 = ks * 128;
    __syncthreads();
#pragma unroll
    for (int it = 0; it < 4; ++it) {
      int ch = w * 256 + it * 64 + lane;
      int row = ch >> 4, cc = ch & 15;
      GLL16(att2 + (size_t)(m0 + row) * 1024 + k0 + ((cc ^ (row & 7)) * 8),
            (char*)As + (w * 256 + it * 64) * 16);
    }
#pragma unroll
    for (int it = 0; it < 8; ++it) {
      int ch = w * 512 + it * 64 + lane;
      int n = ch >> 4, cc = ch & 15;
      GLL16(wmlp_bt + (size_t)n * 1024 + k0 + ((cc ^ (n & 7)) * 8),
            (char*)Bs + (w * 512 + it * 64) * 16);
    }
    __syncthreads();
#pragma unroll
    for (int kk = 0; kk < 4; ++kk) {
      bf16x8 a = *(const bf16x8*)((const char*)As + (16 * w + c) * 256 + (((4 * kk + g) ^ (c & 7)) << 4));
#pragma unroll
      for (int fo = 0; fo < 8; ++fo) {
        bf16x8 b = *(const bf16x8*)((const char*)Bs + (16 * fo + c) * 256 + (((4 * kk + g) ^ (c & 7)) << 4));
        acc[fo] = MFMA(a, b, acc[fo]);
      }
    }
  }
#pragma unroll
  for (int j = 0; j < 4; ++j) {
    int rg = m0 + 16 * w + 4 * g + j;
    float y[8];
    float s1 = 0.f, s2 = 0.f;
#pragma unroll
    for (int fo = 0; fo < 8; ++fo) {
      float v = acc[fo][j] + x[(size_t)rg * 128 + 16 * fo + c];
      y[fo] = v; s1 += v; s2 += v * v;
    }
#pragma unroll
    for (int d = 1; d < 16; d <<= 1) { s1 += __shfl_xor(s1, d); s2 += __shfl_xor(s2, d); }
    float mu = s1 * 0.0078125f;
    float var = s2 * 0.0078125f - mu * mu;
    float rs = rsqrtf(var + 1e-5f);
#pragma unroll
    for (int fo = 0; fo < 8; ++fo) {
      int e = 16 * fo + c;
      out[(size_t)rg * 128 + e] = (y[fo] - mu) * rs * lng[e] + lnb[e];
    }
  }
}

extern "C" void kernel_launch(void* const* d_in, const int* in_sizes, int n_in,
                              void* d_out, int out_size, void* d_ws, size_t ws_size,
                              hipStream_t stream)
{
  const float* x    = (const float*)d_in[0];
  const float* mm   = (const float*)d_in[1];
  const float* u1   = (const float*)d_in[3];
  const float* u2   = (const float*)d_in[4];
  const float* wq   = (const float*)d_in[5];
  const float* wkv  = (const float*)d_in[6];
  const float* wr   = (const float*)d_in[7];
  const float* wmlp = (const float*)d_in[8];
  const float* lng  = (const float*)d_in[9];
  const float* lnb  = (const float*)d_in[10];
  float* out = (float*)d_out;

  char* p = (char*)d_ws;
  bf16* posb    = (bf16*)p;  p += (size_t)262144 * 2;
  bf16* wq_bt   = (bf16*)p;  p += (size_t)131072 * 2;
  bf16* wkv_bt  = (bf16*)p;  p += (size_t)262144 * 2;
  bf16* wr_bt   = (bf16*)p;  p += (size_t)131072 * 2;
  bf16* wmlp_bt = (bf16*)p;  p += (size_t)131072 * 2;
  bf16* xb      = (bf16*)p;  p += (size_t)524288 * 2;
  bf16* memb    = (bf16*)p;  p += (size_t)524288 * 2;
  bf16* qhk     = (bf16*)p;  p += (size_t)4 * 8 * 1024 * 128 * 2;
  bf16* qhr     = (bf16*)p;  p += (size_t)4 * 8 * 1024 * 128 * 2;
  bf16* kh      = (bf16*)p;  p += (size_t)4 * 8 * 2048 * 128 * 2;
  bf16* vh      = (bf16*)p;  p += (size_t)4 * 8 * 2048 * 128 * 2;
  bf16* vht     = (bf16*)p;  p += (size_t)4 * 8 * 2048 * 128 * 2;
  bf16* rhe     = (bf16*)p;  p += (size_t)8 * 2112 * 128 * 2;
  bf16* att2    = (bf16*)p;  p += (size_t)4 * 1024 * 1024 * 2;

  k_prep<<<dim3(4608), dim3(256), 0, stream>>>(x, mm, wq, wkv, wr, wmlp,
                                               posb, wq_bt, wkv_bt, wr_bt, wmlp_bt, xb, memb);
  k_proj<0><<<dim3(64, 8),   dim3(256), 0, stream>>>(xb,  (const bf16*)nullptr, wq_bt,  qhk, qhr, u1, u2);
  k_proj<1><<<dim3(128, 16), dim3(256), 0, stream>>>(xb,  memb,                 wkv_bt, kh,  vh,  nullptr, nullptr);
  k_proj<2><<<dim3(32, 8),   dim3(256), 0, stream>>>(posb,(const bf16*)nullptr, wr_bt,  rhe, (bf16*)nullptr, nullptr, nullptr);
  k_vtrans<<<dim3(32, 2, 32), dim3(256), 0, stream>>>(vh, vht);
  k_flash<<<dim3(512), dim3(256), 0, stream>>>(qhk, qhr, kh, vht, rhe, att2);
  k_mlp<<<dim3(64), dim3(256), 0, stream>>>(att2, wmlp_bt, x, lng, lnb, out);
}